// Round 3
// baseline (2250.367 us; speedup 1.0000x reference)
//
#include <hip/hip_runtime.h>
#include <stdint.h>

#define DEV static __device__ __forceinline__

typedef unsigned short u16x4 __attribute__((ext_vector_type(4)));
typedef unsigned short u16x8 __attribute__((ext_vector_type(8)));

#define B_   2
#define T_   8192
#define D_   1024
#define H_   8
#define HD_  128
#define C_   64
#define N_   128   /* chunks per (b,h) */

DEV float dot4(const float4& a, const float4& b) {
    return a.x * b.x + a.y * b.y + a.z * b.z + a.w * b.w;
}
DEV unsigned short f2bf(float f) {
    union { float f; unsigned u; } v; v.f = f;
    unsigned r = (v.u + 0x7fffu + ((v.u >> 16) & 1u)) >> 16;
    return (unsigned short)r;
}
DEV float bf2f(unsigned short u) {
    union { unsigned u; float f; } v; v.u = ((unsigned)u) << 16;
    return v.f;
}

// Swizzled LDS row helpers. Rows of 512B (128 f32) or 256B (64 f32).
// Swizzle granularity is ONE 16B unit: unit_index ^= (row & 7).
DEV float4* r512(char* base, int r, int u) {
    return (float4*)(base + (r << 9) + ((u << 4) ^ ((r & 7) << 4)));
}
DEV float4* r256(char* base, int r, int u) {
    return (float4*)(base + (r << 8) + ((u << 4) ^ ((r & 7) << 4)));
}
DEV float* addr256s(char* base, int r, int c) {  // scalar f32 in swizzled 256B row
    int u = c >> 2;
    return (float*)(base + (r << 8) + (((u << 4) ^ ((r & 7) << 4)) + ((c & 3) << 2)));
}

// =====================================================================
// Kernel 1: prep — L2-normalized k per head (f32) + beta = sigmoid(x@Wb^T)
// grid: B_*T_ blocks x 256
// =====================================================================
__launch_bounds__(256)
__global__ void prep_kernel(const float* __restrict__ X, const float* __restrict__ Wb,
                            float* __restrict__ kb, float* __restrict__ beta) {
    int bt = blockIdx.x;
    int b = bt >> 13, t = bt & 8191;
    __shared__ float xrow[D_];
    const float* xp = X + (size_t)bt * D_;
    for (int i = threadIdx.x; i < D_; i += 256) xrow[i] = xp[i];
    __syncthreads();
    int w = threadIdx.x >> 6, lane = threadIdx.x & 63;
    for (int h = w; h < H_; h += 4) {
        const float* xh = xrow + h * HD_;
        float a0 = xh[lane], a1 = xh[lane + 64];
        float s = a0 * a0 + a1 * a1;
        #pragma unroll
        for (int off = 32; off > 0; off >>= 1) s += __shfl_xor(s, off);
        float rn = 1.0f / fmaxf(sqrtf(s), 1e-12f);
        const float* wbh = Wb + (size_t)h * D_;
        float bs = 0.f;
        for (int i = lane; i < D_; i += 64) bs += xrow[i] * wbh[i];
        #pragma unroll
        for (int off = 32; off > 0; off >>= 1) bs += __shfl_xor(bs, off);
        float bet = 1.0f / (1.0f + expf(-bs));
        size_t kbase = ((size_t)(b * H_ + h) * T_ + t) * HD_;
        kb[kbase + lane]      = a0 * rn;
        kb[kbase + lane + 64] = a1 * rn;
        if (lane == 0) beta[(size_t)(b * H_ + h) * T_ + t] = bet;
    }
}

// =====================================================================
// Kernel 2: vproj — v = beta * (x @ W_write^T) -> f32 [bh][t][d]
// f32 tiled GEMM 128x128x16, 256 thr, 8x8/thread. grid (128, 8)
// =====================================================================
__launch_bounds__(256, 2)
__global__ void vproj_kernel(const float* __restrict__ X, const float* __restrict__ W,
                             const float* __restrict__ beta, float* __restrict__ vb) {
    __shared__ float As[16][128];
    __shared__ float Bs[16][128];
    int bm = blockIdx.x, bn = blockIdx.y;
    int tid = threadIdx.x;
    int tx = tid & 15, ty = tid >> 4;
    float acc[8][8] = {};
    const float* Ag = X + (size_t)bm * 128 * D_;
    const float* Bg = W + (size_t)bn * 128 * D_;
    for (int kt = 0; kt < 64; ++kt) {
        #pragma unroll
        for (int l = 0; l < 2; ++l) {
            int s = tid + l * 256;
            int row = s >> 2, c4 = (s & 3) << 2;
            float4 av = *(const float4*)(Ag + (size_t)row * D_ + kt * 16 + c4);
            float4 bv = *(const float4*)(Bg + (size_t)row * D_ + kt * 16 + c4);
            As[c4 + 0][row] = av.x; As[c4 + 1][row] = av.y; As[c4 + 2][row] = av.z; As[c4 + 3][row] = av.w;
            Bs[c4 + 0][row] = bv.x; Bs[c4 + 1][row] = bv.y; Bs[c4 + 2][row] = bv.z; Bs[c4 + 3][row] = bv.w;
        }
        __syncthreads();
        #pragma unroll
        for (int kk = 0; kk < 16; ++kk) {
            float4 a0 = *(const float4*)&As[kk][ty * 8];
            float4 a1 = *(const float4*)&As[kk][ty * 8 + 4];
            float4 b0 = *(const float4*)&Bs[kk][tx * 8];
            float4 b1 = *(const float4*)&Bs[kk][tx * 8 + 4];
            float a[8] = {a0.x, a0.y, a0.z, a0.w, a1.x, a1.y, a1.z, a1.w};
            float bb[8] = {b0.x, b0.y, b0.z, b0.w, b1.x, b1.y, b1.z, b1.w};
            #pragma unroll
            for (int r = 0; r < 8; ++r)
                #pragma unroll
                for (int c = 0; c < 8; ++c)
                    acc[r][c] = fmaf(a[r], bb[c], acc[r][c]);
        }
        __syncthreads();
    }
    int m0 = bm * 128 + ty * 8;
    #pragma unroll
    for (int r = 0; r < 8; ++r) {
        int m = m0 + r;
        int bb_ = m >> 13, t = m & 8191;
        float bet = beta[(size_t)(bb_ * H_ + bn) * T_ + t];
        size_t ob = ((size_t)(bb_ * H_ + bn) * T_ + t) * HD_ + tx * 8;
        float4 o0 = {acc[r][0] * bet, acc[r][1] * bet, acc[r][2] * bet, acc[r][3] * bet};
        float4 o1 = {acc[r][4] * bet, acc[r][5] * bet, acc[r][6] * bet, acc[r][7] * bet};
        *(float4*)(vb + ob)     = o0;
        *(float4*)(vb + ob + 4) = o1;
    }
}

// =====================================================================
// Kernel 3: chunk — per-chunk dots, attn(bf16), M=(I-A0), A=M^{-1},
//   kcd = A@(k_beta*gamma^{p+1}),  v' = A@v (overwrites vb).
// grid 2048 blocks x 256, dyn LDS 64KB.
// =====================================================================
__launch_bounds__(256, 2)
__global__ void chunk_kernel(const float* __restrict__ kb,
                             float* __restrict__ vb,        // in: v, out: v'
                             const float* __restrict__ beta_g,
                             const float* __restrict__ decay,
                             unsigned short* __restrict__ attn_g,
                             float* __restrict__ kcd_g) {
    extern __shared__ char cs[];
    char*  sk = cs;                      // [64][128] f32 swz (32KB); later reused for v
    float* sa = (float*)(cs + 32768);    // [64][64] A = M^{-1}
    float* sm = (float*)(cs + 49152);    // [64][64] M
    __shared__ float sb[64];
    __shared__ float swgt[64];

    int cid = blockIdx.x;
    int bh = cid >> 7, cn = cid & 127;
    int h = bh & 7;
    int tid = threadIdx.x;
    float dec = decay[h];
    float sg = 1.0f / (1.0f + expf(-dec));
    float lg = logf(sg);                 // log(sigmoid(decay))
    size_t base = (size_t)cid * 8192;

    // stage k chunk (f32, swizzled per 16B unit)
    #pragma unroll
    for (int lq = 0; lq < 8; ++lq) {
        int f = tid + lq * 256;          // 0..2047 float4s
        int r = f >> 5, u = f & 31;
        *r512(sk, r, u) = ((const float4*)(kb + base))[f];
    }
    if (tid < 64) {
        float bv = beta_g[(size_t)bh * T_ + cn * 64 + tid];
        sb[tid] = bv;
        swgt[tid] = bv * expf((float)(tid + 1) * lg);
    }
    __syncthreads();

    // ---- dots: k_i . k_j. Thread tile: rows I=bi*4+i, rows J=bj+16*j ----
    int bi = tid >> 4, bj = tid & 15;
    float dacc[4][4] = {};
    for (int u = 0; u < 32; ++u) {
        float4 ka[4], kc[4];
        #pragma unroll
        for (int i = 0; i < 4; ++i) ka[i] = *r512(sk, bi * 4 + i, u);
        #pragma unroll
        for (int j = 0; j < 4; ++j) kc[j] = *r512(sk, bj + 16 * j, u);
        #pragma unroll
        for (int i = 0; i < 4; ++i)
            #pragma unroll
            for (int j = 0; j < 4; ++j)
                dacc[i][j] += dot4(ka[i], kc[j]);
    }
    size_t abase = (size_t)cid * 4096;
    #pragma unroll
    for (int i = 0; i < 4; ++i) {
        int gi = bi * 4 + i;
        #pragma unroll
        for (int j = 0; j < 4; ++j) {
            int gj = bj + 16 * j;
            float dv = dacc[i][j];
            float dfac = expf((float)(gi - gj) * lg);
            attn_g[abase + (size_t)gi * 64 + gj] = (gi >= gj) ? f2bf(dv * dfac) : (unsigned short)0;
            sm[gi * 64 + gj] = (gj < gi) ? sb[gi] * dv * dfac : ((gi == gj) ? 1.f : 0.f);
        }
    }
    __syncthreads();

    // ---- invert unit-lower M: one column per thread ----
    if (tid < 64) {
        int j = tid;
        for (int i = 0; i < j; ++i) sa[i * 64 + j] = 0.f;
        sa[j * 64 + j] = 1.f;
        for (int i = j + 1; i < 64; ++i) {
            float s = 0.f;
            for (int p = j; p < i; ++p) s += sm[i * 64 + p] * sa[p * 64 + j];
            sa[i * 64 + j] = -s;
        }
    }
    __syncthreads();

    int ti = tid >> 4, te = tid & 15;
    // ---- kcd = A @ (k_beta * gamma^{p+1})  (needs sk; do before v staging) ----
    {
        float ko[4][8] = {};
        for (int p = 0; p < 64; ++p) {
            float w = swgt[p];
            float4 k0 = *r512(sk, p, te * 2);
            float4 k1 = *r512(sk, p, te * 2 + 1);
            float kv[8] = {k0.x, k0.y, k0.z, k0.w, k1.x, k1.y, k1.z, k1.w};
            float a0 = sa[(ti * 4 + 0) * 64 + p] * w;
            float a1 = sa[(ti * 4 + 1) * 64 + p] * w;
            float a2 = sa[(ti * 4 + 2) * 64 + p] * w;
            float a3 = sa[(ti * 4 + 3) * 64 + p] * w;
            #pragma unroll
            for (int e = 0; e < 8; ++e) {
                ko[0][e] = fmaf(a0, kv[e], ko[0][e]);
                ko[1][e] = fmaf(a1, kv[e], ko[1][e]);
                ko[2][e] = fmaf(a2, kv[e], ko[2][e]);
                ko[3][e] = fmaf(a3, kv[e], ko[3][e]);
            }
        }
        #pragma unroll
        for (int i = 0; i < 4; ++i) {
            float4 lo = {ko[i][0], ko[i][1], ko[i][2], ko[i][3]};
            float4 hi = {ko[i][4], ko[i][5], ko[i][6], ko[i][7]};
            size_t off = base + (size_t)(ti * 4 + i) * 128 + te * 8;
            *(float4*)(kcd_g + off)     = lo;
            *(float4*)(kcd_g + off + 4) = hi;
        }
    }
    __syncthreads();

    // stage v chunk over sk region
    #pragma unroll
    for (int lq = 0; lq < 8; ++lq) {
        int f = tid + lq * 256;
        int r = f >> 5, u = f & 31;
        *r512(sk, r, u) = ((const float4*)(vb + base))[f];
    }
    __syncthreads();

    // ---- v' = A @ v  (write back to vb) ----
    {
        float vo[4][8] = {};
        for (int p = 0; p < 64; ++p) {
            float4 v0 = *r512(sk, p, te * 2);
            float4 v1 = *r512(sk, p, te * 2 + 1);
            float vv[8] = {v0.x, v0.y, v0.z, v0.w, v1.x, v1.y, v1.z, v1.w};
            float a0 = sa[(ti * 4 + 0) * 64 + p];
            float a1 = sa[(ti * 4 + 1) * 64 + p];
            float a2 = sa[(ti * 4 + 2) * 64 + p];
            float a3 = sa[(ti * 4 + 3) * 64 + p];
            #pragma unroll
            for (int e = 0; e < 8; ++e) {
                vo[0][e] = fmaf(a0, vv[e], vo[0][e]);
                vo[1][e] = fmaf(a1, vv[e], vo[1][e]);
                vo[2][e] = fmaf(a2, vv[e], vo[2][e]);
                vo[3][e] = fmaf(a3, vv[e], vo[3][e]);
            }
        }
        #pragma unroll
        for (int i = 0; i < 4; ++i) {
            float4 lo = {vo[i][0], vo[i][1], vo[i][2], vo[i][3]};
            float4 hi = {vo[i][4], vo[i][5], vo[i][6], vo[i][7]};
            size_t off = base + (size_t)(ti * 4 + i) * 128 + te * 8;
            *(float4*)(vb + off)     = lo;
            *(float4*)(vb + off + 4) = hi;
        }
    }
}

// =====================================================================
// Kernel 4: scan — sequential over 128 chunks, f32, split by value-dim.
//   v_new[c][e] = v'[c][e] - sum_dk kcd[c][dk] S[dk][e]
//   o[c][e]     = dev[c]*sum_dk k[c][dk] S[dk][e] + sum_j attn[c][j] v_new[j][e]
//   S[dk][e]    = g64*S[dk][e] + sum_c k[c][dk]*dwv[c]*v_new[c][e]
// grid 256 = 16 bh x 16 e-groups (8 cols each), 256 thr, dyn LDS 88KB.
// =====================================================================
__launch_bounds__(256, 1)
__global__ void scan_kernel(const float* __restrict__ kb,
                            const float* __restrict__ vpr,     // v' (overwritten vb)
                            const float* __restrict__ kcd_g,
                            const unsigned short* __restrict__ attn_g,
                            const float* __restrict__ decay,
                            unsigned short* __restrict__ obuf) {
    extern __shared__ char ls[];
    char*  sk   = ls;                    // [64][128] f32 swz   32KB
    char*  skcd = ls + 32768;            // [64][128] f32 swz   32KB
    char*  satt = ls + 65536;            // [64][64]  f32 swz   16KB
    char*  sst  = ls + 81920;            // S^T [8][128] f32 swz 4KB
    char*  svnt = ls + 86016;            // v_new^T [8][64] swz  2KB
    float* svp  = (float*)(ls + 88064);  // v' slice [64][8]     2KB
    __shared__ float sdev[64];
    __shared__ float sdwv[64];

    int bid = blockIdx.x;
    int bh = bid >> 4, eg = bid & 15, e0 = eg * 8;
    int tid = threadIdx.x;
    float dec = decay[bh & 7];
    float sg = 1.0f / (1.0f + expf(-dec));
    float lg = logf(sg);
    float g64 = expf(64.f * lg);
    if (tid < 64) {
        sdev[tid] = expf((float)(tid + 1) * lg);   // gamma^{c+1}
        sdwv[tid] = expf((float)(63 - tid) * lg);  // gamma^{63-c}
    }
    ((float4*)sst)[tid] = make_float4(0.f, 0.f, 0.f, 0.f);  // zero S (4KB)
    __syncthreads();

    for (int cn = 0; cn < N_; ++cn) {
        size_t cid = (size_t)bh * N_ + cn;
        const float4* gk   = (const float4*)(kb    + cid * 8192);
        const float4* gkcd = (const float4*)(kcd_g + cid * 8192);
        const u16x8*  gat  = (const u16x8*)(attn_g + cid * 4096);
        // ---- stage ----
        #pragma unroll
        for (int lq = 0; lq < 8; ++lq) {
            int f = tid + lq * 256, r = f >> 5, u = f & 31;
            *r512(sk, r, u)   = gk[f];
            *r512(skcd, r, u) = gkcd[f];
        }
        #pragma unroll
        for (int lq = 0; lq < 2; ++lq) {
            int f = tid + lq * 256;          // 0..511, 8 u16 each
            u16x8 raw = gat[f];
            float4 lo = {bf2f(raw[0]), bf2f(raw[1]), bf2f(raw[2]), bf2f(raw[3])};
            float4 hi = {bf2f(raw[4]), bf2f(raw[5]), bf2f(raw[6]), bf2f(raw[7])};
            int r = f >> 3, cu = (f & 7) << 1;
            *r256(satt, r, cu)     = lo;
            *r256(satt, r, cu + 1) = hi;
        }
        if (tid < 128) {
            int c = tid >> 1, hf = tid & 1;
            float4 v = *(const float4*)(vpr + cid * 8192 + (size_t)c * 128 + e0 + hf * 4);
            *(float4*)(svp + c * 8 + hf * 4) = v;
        }
        __syncthreads();

        // ---- p1: v_new (tile 2c x 2e per thread, threads < 128) ----
        if (tid < 128) {
            int c0 = tid >> 2, e1 = tid & 3;
            float a00 = 0, a01 = 0, a10 = 0, a11 = 0;
            for (int u = 0; u < 32; ++u) {
                float4 x0 = *r512(skcd, c0, u);
                float4 x1 = *r512(skcd, c0 + 32, u);
                float4 s0 = *r512(sst, e1, u);
                float4 s1 = *r512(sst, e1 + 4, u);
                a00 += dot4(x0, s0); a01 += dot4(x0, s1);
                a10 += dot4(x1, s0); a11 += dot4(x1, s1);
            }
            *addr256s(svnt, e1,     c0)      = svp[c0 * 8 + e1]            - a00;
            *addr256s(svnt, e1 + 4, c0)      = svp[c0 * 8 + e1 + 4]        - a01;
            *addr256s(svnt, e1,     c0 + 32) = svp[(c0 + 32) * 8 + e1]     - a10;
            *addr256s(svnt, e1 + 4, c0 + 32) = svp[(c0 + 32) * 8 + e1 + 4] - a11;
        }
        __syncthreads();

        // ---- p2: o = dev[c]*(k@S) + attn@v_new ----
        if (tid < 128) {
            int c0 = tid >> 2, e1 = tid & 3;
            float a00 = 0, a01 = 0, a10 = 0, a11 = 0;
            for (int u = 0; u < 32; ++u) {
                float4 x0 = *r512(sk, c0, u);
                float4 x1 = *r512(sk, c0 + 32, u);
                float4 s0 = *r512(sst, e1, u);
                float4 s1 = *r512(sst, e1 + 4, u);
                a00 += dot4(x0, s0); a01 += dot4(x0, s1);
                a10 += dot4(x1, s0); a11 += dot4(x1, s1);
            }
            float d0 = sdev[c0], d1 = sdev[c0 + 32];
            float o00 = a00 * d0, o01 = a01 * d0;
            float o10 = a10 * d1, o11 = a11 * d1;
            for (int u = 0; u < 16; ++u) {
                float4 t0 = *r256(satt, c0, u);
                float4 t1 = *r256(satt, c0 + 32, u);
                float4 v0 = *r256(svnt, e1, u);
                float4 v1 = *r256(svnt, e1 + 4, u);
                o00 += dot4(t0, v0); o01 += dot4(t0, v1);
                o10 += dot4(t1, v0); o11 += dot4(t1, v1);
            }
            unsigned short* ob = obuf + ((size_t)bh * T_ + (size_t)cn * 64) * 128 + e0;
            ob[(size_t)c0 * 128 + e1]            = f2bf(o00);
            ob[(size_t)c0 * 128 + e1 + 4]        = f2bf(o01);
            ob[(size_t)(c0 + 32) * 128 + e1]     = f2bf(o10);
            ob[(size_t)(c0 + 32) * 128 + e1 + 4] = f2bf(o11);
        }
        __syncthreads();

        // ---- p3: S^T update (all 256 threads; thread owns (e, 4 dk)) ----
        {
            int e = tid >> 5, dkg = tid & 31;
            float4 upd = {0.f, 0.f, 0.f, 0.f};
            for (int c = 0; c < 64; ++c) {
                float4 kv = *r512(sk, c, dkg);
                float m = (*addr256s(svnt, e, c)) * sdwv[c];
                upd.x = fmaf(kv.x, m, upd.x);
                upd.y = fmaf(kv.y, m, upd.y);
                upd.z = fmaf(kv.z, m, upd.z);
                upd.w = fmaf(kv.w, m, upd.w);
            }
            float4* sp = r512(sst, e, dkg);
            float4 s = *sp;
            s.x = fmaf(s.x, g64, upd.x);
            s.y = fmaf(s.y, g64, upd.y);
            s.z = fmaf(s.z, g64, upd.z);
            s.w = fmaf(s.w, g64, upd.w);
            *sp = s;
        }
        __syncthreads();
    }
}

// =====================================================================
// Kernel 5: final — out = x + o @ W_read^T. f32 GEMM, A gathered from
// bf16 obuf. grid (128, 8)
// =====================================================================
__launch_bounds__(256, 2)
__global__ void final_kernel(const float* __restrict__ X, const float* __restrict__ W,
                             const unsigned short* __restrict__ OB, float* __restrict__ out) {
    __shared__ float As[16][128];
    __shared__ float Bs[16][128];
    int bm = blockIdx.x, bn = blockIdx.y;
    int tid = threadIdx.x;
    int tx = tid & 15, ty = tid >> 4;
    float acc[8][8] = {};
    const float* Bg = W + (size_t)bn * 128 * D_;
    for (int kt = 0; kt < 64; ++kt) {
        int hh = kt >> 3;
        #pragma unroll
        for (int l = 0; l < 2; ++l) {
            int s = tid + l * 256;
            int row = s >> 2, c4 = (s & 3) << 2;
            int m = bm * 128 + row;
            int bb_ = m >> 13, t = m & 8191;
            int e0 = ((kt & 7) << 4) + c4;
            u16x4 av = *(const u16x4*)(OB + (((size_t)(bb_ * H_ + hh) * T_ + t) << 7) + e0);
            float4 bv = *(const float4*)(Bg + (size_t)row * D_ + kt * 16 + c4);
            As[c4 + 0][row] = bf2f(av[0]); As[c4 + 1][row] = bf2f(av[1]);
            As[c4 + 2][row] = bf2f(av[2]); As[c4 + 3][row] = bf2f(av[3]);
            Bs[c4 + 0][row] = bv.x; Bs[c4 + 1][row] = bv.y; Bs[c4 + 2][row] = bv.z; Bs[c4 + 3][row] = bv.w;
        }
        __syncthreads();
        #pragma unroll
        for (int kk = 0; kk < 16; ++kk) {
            float4 a0 = *(const float4*)&As[kk][ty * 8];
            float4 a1 = *(const float4*)&As[kk][ty * 8 + 4];
            float4 b0 = *(const float4*)&Bs[kk][tx * 8];
            float4 b1 = *(const float4*)&Bs[kk][tx * 8 + 4];
            float a[8] = {a0.x, a0.y, a0.z, a0.w, a1.x, a1.y, a1.z, a1.w};
            float bb[8] = {b0.x, b0.y, b0.z, b0.w, b1.x, b1.y, b1.z, b1.w};
            #pragma unroll
            for (int r = 0; r < 8; ++r)
                #pragma unroll
                for (int c = 0; c < 8; ++c)
                    acc[r][c] = fmaf(a[r], bb[c], acc[r][c]);
        }
        __syncthreads();
    }
    int m0 = bm * 128 + ty * 8;
    #pragma unroll
    for (int r = 0; r < 8; ++r) {
        int m = m0 + r;
        size_t xoff = (size_t)m * D_ + bn * 128 + tx * 8;
        float4 x0 = *(const float4*)(X + xoff);
        float4 x1 = *(const float4*)(X + xoff + 4);
        float4 o0 = {x0.x + acc[r][0], x0.y + acc[r][1], x0.z + acc[r][2], x0.w + acc[r][3]};
        float4 o1 = {x1.x + acc[r][4], x1.y + acc[r][5], x1.z + acc[r][6], x1.w + acc[r][7]};
        *(float4*)(out + xoff)     = o0;
        *(float4*)(out + xoff + 4) = o1;
    }
}

// =====================================================================
extern "C" void kernel_launch(void* const* d_in, const int* in_sizes, int n_in,
                              void* d_out, int out_size, void* d_ws, size_t ws_size,
                              hipStream_t stream) {
    const float* X   = (const float*)d_in[0];
    const float* Ww  = (const float*)d_in[1];
    const float* Wr  = (const float*)d_in[2];
    const float* Wb  = (const float*)d_in[3];
    const float* dec = (const float*)d_in[4];

    // workspace layout (bytes). f32 recurrence path; bf16 for attn & o.
    const size_t SZ = (size_t)B_ * H_ * T_ * HD_ * 4;      // 67,108,864
    char* ws = (char*)d_ws;
    float*          kb   = (float*)(ws);                   // 64MB  normalized k
    float*          vb   = (float*)(ws + SZ);              // 64MB  v, then v'
    float*          kcd  = (float*)(ws + 2 * SZ);          // 64MB
    unsigned short* attn = (unsigned short*)(ws + 3 * SZ); // 16MB  bf16
    float*          beta = (float*)(ws + 3 * SZ + 16777216);             // 0.5MB
    unsigned short* obuf = (unsigned short*)(ws + 3 * SZ + 17301504);    // 32MB bf16
    const size_t needed = 3 * SZ + 17301504 + 33554432;    // 252,183,040... (see below)
    // exact: 201326592 + 16777216 + 524288 + 33554432 = 252,182,528
    if (ws_size < 252182528ull) return;

    hipFuncSetAttribute((const void*)chunk_kernel, hipFuncAttributeMaxDynamicSharedMemorySize, 65536);
    hipFuncSetAttribute((const void*)scan_kernel,  hipFuncAttributeMaxDynamicSharedMemorySize, 90112);
    (void)needed;

    hipLaunchKernelGGL(prep_kernel, dim3(B_ * T_), dim3(256), 0, stream, X, Wb, kb, beta);
    hipLaunchKernelGGL(vproj_kernel, dim3(128, 8), dim3(256), 0, stream, X, Ww, beta, vb);
    hipLaunchKernelGGL(chunk_kernel, dim3(B_ * H_ * N_), dim3(256), 65536, stream,
                       kb, vb, beta, dec, attn, kcd);
    hipLaunchKernelGGL(scan_kernel, dim3(256), dim3(256), 90112, stream,
                       kb, vb, kcd, attn, dec, obuf);
    hipLaunchKernelGGL(final_kernel, dim3(128, 8), dim3(256), 0, stream, X, Wr, obuf, (float*)d_out);
}

// Round 4
// 1566.068 us; speedup vs baseline: 1.4370x; 1.4370x over previous
//
#include <hip/hip_runtime.h>
#include <stdint.h>

#define DEV static __device__ __forceinline__

typedef float          f32x4  __attribute__((ext_vector_type(4)));
typedef short          bf16x8 __attribute__((ext_vector_type(8)));
typedef unsigned short u16x4  __attribute__((ext_vector_type(4)));
typedef unsigned short u16x8  __attribute__((ext_vector_type(8)));

#define B_   2
#define T_   8192
#define D_   1024
#define H_   8
#define HD_  128
#define N_   128   /* chunks per (b,h) */

DEV float dot4(const float4& a, const float4& b) {
    return a.x * b.x + a.y * b.y + a.z * b.z + a.w * b.w;
}
DEV unsigned short f2bf(float f) {
    union { float f; unsigned u; } v; v.f = f;
    unsigned r = (v.u + 0x7fffu + ((v.u >> 16) & 1u)) >> 16;
    return (unsigned short)r;
}
DEV float bf2f(unsigned short u) {
    union { unsigned u; float f; } v; v.u = ((unsigned)u) << 16;
    return v.f;
}

// Swizzled LDS rows of 512B (128 f32); swizzle per 16B unit: unit ^= (row&7).
DEV float4* r512(char* base, int r, int u) {
    return (float4*)(base + (r << 9) + ((u << 4) ^ ((r & 7) << 4)));
}

// =====================================================================
// Kernel 1: prep — L2-normalized k per head -> bf16 hi/lo; beta.
// grid: B_*T_ blocks x 256
// =====================================================================
__launch_bounds__(256)
__global__ void prep_kernel(const float* __restrict__ X, const float* __restrict__ Wb,
                            unsigned short* __restrict__ khi, unsigned short* __restrict__ klo,
                            float* __restrict__ beta) {
    int bt = blockIdx.x;
    int b = bt >> 13, t = bt & 8191;
    __shared__ float xrow[D_];
    const float* xp = X + (size_t)bt * D_;
    for (int i = threadIdx.x; i < D_; i += 256) xrow[i] = xp[i];
    __syncthreads();
    int w = threadIdx.x >> 6, lane = threadIdx.x & 63;
    for (int h = w; h < H_; h += 4) {
        const float* xh = xrow + h * HD_;
        float a0 = xh[lane], a1 = xh[lane + 64];
        float s = a0 * a0 + a1 * a1;
        #pragma unroll
        for (int off = 32; off > 0; off >>= 1) s += __shfl_xor(s, off);
        float rn = 1.0f / fmaxf(sqrtf(s), 1e-12f);
        const float* wbh = Wb + (size_t)h * D_;
        float bs = 0.f;
        for (int i = lane; i < D_; i += 64) bs += xrow[i] * wbh[i];
        #pragma unroll
        for (int off = 32; off > 0; off >>= 1) bs += __shfl_xor(bs, off);
        float bet = 1.0f / (1.0f + expf(-bs));
        size_t kbase = ((size_t)(b * H_ + h) * T_ + t) * HD_;
        float x0 = a0 * rn, x1 = a1 * rn;
        unsigned short h0 = f2bf(x0), h1 = f2bf(x1);
        khi[kbase + lane]      = h0;
        khi[kbase + lane + 64] = h1;
        klo[kbase + lane]      = f2bf(x0 - bf2f(h0));
        klo[kbase + lane + 64] = f2bf(x1 - bf2f(h1));
        if (lane == 0) beta[(size_t)(b * H_ + h) * T_ + t] = bet;
    }
}

// =====================================================================
// Kernel 2: vproj — v = beta * (x @ W_write^T) -> f32 [bh][t][d]
// =====================================================================
__launch_bounds__(256, 2)
__global__ void vproj_kernel(const float* __restrict__ X, const float* __restrict__ W,
                             const float* __restrict__ beta, float* __restrict__ vb) {
    __shared__ float As[16][128];
    __shared__ float Bs[16][128];
    int bm = blockIdx.x, bn = blockIdx.y;
    int tid = threadIdx.x;
    int tx = tid & 15, ty = tid >> 4;
    float acc[8][8] = {};
    const float* Ag = X + (size_t)bm * 128 * D_;
    const float* Bg = W + (size_t)bn * 128 * D_;
    for (int kt = 0; kt < 64; ++kt) {
        #pragma unroll
        for (int l = 0; l < 2; ++l) {
            int s = tid + l * 256;
            int row = s >> 2, c4 = (s & 3) << 2;
            float4 av = *(const float4*)(Ag + (size_t)row * D_ + kt * 16 + c4);
            float4 bv = *(const float4*)(Bg + (size_t)row * D_ + kt * 16 + c4);
            As[c4 + 0][row] = av.x; As[c4 + 1][row] = av.y; As[c4 + 2][row] = av.z; As[c4 + 3][row] = av.w;
            Bs[c4 + 0][row] = bv.x; Bs[c4 + 1][row] = bv.y; Bs[c4 + 2][row] = bv.z; Bs[c4 + 3][row] = bv.w;
        }
        __syncthreads();
        #pragma unroll
        for (int kk = 0; kk < 16; ++kk) {
            float4 a0 = *(const float4*)&As[kk][ty * 8];
            float4 a1 = *(const float4*)&As[kk][ty * 8 + 4];
            float4 b0 = *(const float4*)&Bs[kk][tx * 8];
            float4 b1 = *(const float4*)&Bs[kk][tx * 8 + 4];
            float a[8] = {a0.x, a0.y, a0.z, a0.w, a1.x, a1.y, a1.z, a1.w};
            float bb[8] = {b0.x, b0.y, b0.z, b0.w, b1.x, b1.y, b1.z, b1.w};
            #pragma unroll
            for (int r = 0; r < 8; ++r)
                #pragma unroll
                for (int c = 0; c < 8; ++c)
                    acc[r][c] = fmaf(a[r], bb[c], acc[r][c]);
        }
        __syncthreads();
    }
    int m0 = bm * 128 + ty * 8;
    #pragma unroll
    for (int r = 0; r < 8; ++r) {
        int m = m0 + r;
        int bb_ = m >> 13, t = m & 8191;
        float bet = beta[(size_t)(bb_ * H_ + bn) * T_ + t];
        size_t ob = ((size_t)(bb_ * H_ + bn) * T_ + t) * HD_ + tx * 8;
        float4 o0 = {acc[r][0] * bet, acc[r][1] * bet, acc[r][2] * bet, acc[r][3] * bet};
        float4 o1 = {acc[r][4] * bet, acc[r][5] * bet, acc[r][6] * bet, acc[r][7] * bet};
        *(float4*)(vb + ob)     = o0;
        *(float4*)(vb + ob + 4) = o1;
    }
}

// =====================================================================
// Kernel 3: chunk — dots, attn(bf16), M, A=M^{-1},
//   kcd-negated (bf16 hi/lo), v' = A@v (f32 in place).
// grid 2048 x 256, dyn LDS 64KB.
// =====================================================================
__launch_bounds__(256, 2)
__global__ void chunk_kernel(const unsigned short* __restrict__ khi,
                             const unsigned short* __restrict__ klo,
                             float* __restrict__ vb,
                             const float* __restrict__ beta_g,
                             const float* __restrict__ decay,
                             unsigned short* __restrict__ attn_g,
                             unsigned short* __restrict__ kcdhi_g,
                             unsigned short* __restrict__ kcdlo_g) {
    extern __shared__ char cs[];
    char*  sk = cs;                      // [64][128] f32 swz (32KB); later reused for v
    float* sa = (float*)(cs + 32768);    // [64][64] A
    float* sm = (float*)(cs + 49152);    // [64][64] M
    __shared__ float sb[64];
    __shared__ float swgt[64];

    int cid = blockIdx.x;
    int bh = cid >> 7, cn = cid & 127;
    int h = bh & 7;
    int tid = threadIdx.x;
    float dec = decay[h];
    float sg = 1.0f / (1.0f + expf(-dec));
    float lg = logf(sg);
    size_t base = (size_t)cid * 8192;

    // stage k chunk (hi+lo -> f32, swizzled)
    #pragma unroll
    for (int lq = 0; lq < 4; ++lq) {
        int f = tid + lq * 256;            // 0..1023, 8 floats each
        int c = f >> 4, u0 = (f & 15) << 1;
        u16x8 hh = *(const u16x8*)(khi + base + (size_t)f * 8);
        u16x8 ll = *(const u16x8*)(klo + base + (size_t)f * 8);
        float4 v0 = {bf2f(hh[0]) + bf2f(ll[0]), bf2f(hh[1]) + bf2f(ll[1]),
                     bf2f(hh[2]) + bf2f(ll[2]), bf2f(hh[3]) + bf2f(ll[3])};
        float4 v1 = {bf2f(hh[4]) + bf2f(ll[4]), bf2f(hh[5]) + bf2f(ll[5]),
                     bf2f(hh[6]) + bf2f(ll[6]), bf2f(hh[7]) + bf2f(ll[7])};
        *r512(sk, c, u0)     = v0;
        *r512(sk, c, u0 + 1) = v1;
    }
    if (tid < 64) {
        float bv = beta_g[(size_t)bh * T_ + cn * 64 + tid];
        sb[tid] = bv;
        swgt[tid] = bv * expf((float)(tid + 1) * lg);
    }
    __syncthreads();

    // ---- dots: k_i . k_j ----
    int bi = tid >> 4, bj = tid & 15;
    float dacc[4][4] = {};
    for (int u = 0; u < 32; ++u) {
        float4 ka[4], kc[4];
        #pragma unroll
        for (int i = 0; i < 4; ++i) ka[i] = *r512(sk, bi * 4 + i, u);
        #pragma unroll
        for (int j = 0; j < 4; ++j) kc[j] = *r512(sk, bj + 16 * j, u);
        #pragma unroll
        for (int i = 0; i < 4; ++i)
            #pragma unroll
            for (int j = 0; j < 4; ++j)
                dacc[i][j] += dot4(ka[i], kc[j]);
    }
    size_t abase = (size_t)cid * 4096;
    #pragma unroll
    for (int i = 0; i < 4; ++i) {
        int gi = bi * 4 + i;
        #pragma unroll
        for (int j = 0; j < 4; ++j) {
            int gj = bj + 16 * j;
            float dv = dacc[i][j];
            float dfac = expf((float)(gi - gj) * lg);
            attn_g[abase + (size_t)gi * 64 + gj] = (gi >= gj) ? f2bf(dv * dfac) : (unsigned short)0;
            sm[gi * 64 + gj] = (gj < gi) ? sb[gi] * dv * dfac : ((gi == gj) ? 1.f : 0.f);
        }
    }
    __syncthreads();

    // ---- invert unit-lower M ----
    if (tid < 64) {
        int j = tid;
        for (int i = 0; i < j; ++i) sa[i * 64 + j] = 0.f;
        sa[j * 64 + j] = 1.f;
        for (int i = j + 1; i < 64; ++i) {
            float s = 0.f;
            for (int p = j; p < i; ++p) s += sm[i * 64 + p] * sa[p * 64 + j];
            sa[i * 64 + j] = -s;
        }
    }
    __syncthreads();

    int ti = tid >> 4, te = tid & 15;
    // ---- kcd(negated) = -(A @ (k_beta * gamma^{p+1})) -> bf16 hi/lo ----
    {
        float ko[4][8] = {};
        for (int p = 0; p < 64; ++p) {
            float w = swgt[p];
            float4 k0 = *r512(sk, p, te * 2);
            float4 k1 = *r512(sk, p, te * 2 + 1);
            float kv[8] = {k0.x, k0.y, k0.z, k0.w, k1.x, k1.y, k1.z, k1.w};
            float a0 = sa[(ti * 4 + 0) * 64 + p] * w;
            float a1 = sa[(ti * 4 + 1) * 64 + p] * w;
            float a2 = sa[(ti * 4 + 2) * 64 + p] * w;
            float a3 = sa[(ti * 4 + 3) * 64 + p] * w;
            #pragma unroll
            for (int e = 0; e < 8; ++e) {
                ko[0][e] = fmaf(a0, kv[e], ko[0][e]);
                ko[1][e] = fmaf(a1, kv[e], ko[1][e]);
                ko[2][e] = fmaf(a2, kv[e], ko[2][e]);
                ko[3][e] = fmaf(a3, kv[e], ko[3][e]);
            }
        }
        #pragma unroll
        for (int i = 0; i < 4; ++i) {
            u16x8 hh, ll;
            #pragma unroll
            for (int e = 0; e < 8; ++e) {
                float t = -ko[i][e];
                unsigned short hv = f2bf(t);
                hh[e] = hv;
                ll[e] = f2bf(t - bf2f(hv));
            }
            size_t off = base + (size_t)(ti * 4 + i) * 128 + te * 8;
            *(u16x8*)(kcdhi_g + off) = hh;
            *(u16x8*)(kcdlo_g + off) = ll;
        }
    }
    __syncthreads();

    // stage v chunk over sk region
    #pragma unroll
    for (int lq = 0; lq < 8; ++lq) {
        int f = tid + lq * 256;
        int r = f >> 5, u = f & 31;
        *r512(sk, r, u) = ((const float4*)(vb + base))[f];
    }
    __syncthreads();

    // ---- v' = A @ v (f32, in place) ----
    {
        float vo[4][8] = {};
        for (int p = 0; p < 64; ++p) {
            float4 v0 = *r512(sk, p, te * 2);
            float4 v1 = *r512(sk, p, te * 2 + 1);
            float vv[8] = {v0.x, v0.y, v0.z, v0.w, v1.x, v1.y, v1.z, v1.w};
            float a0 = sa[(ti * 4 + 0) * 64 + p];
            float a1 = sa[(ti * 4 + 1) * 64 + p];
            float a2 = sa[(ti * 4 + 2) * 64 + p];
            float a3 = sa[(ti * 4 + 3) * 64 + p];
            #pragma unroll
            for (int e = 0; e < 8; ++e) {
                vo[0][e] = fmaf(a0, vv[e], vo[0][e]);
                vo[1][e] = fmaf(a1, vv[e], vo[1][e]);
                vo[2][e] = fmaf(a2, vv[e], vo[2][e]);
                vo[3][e] = fmaf(a3, vv[e], vo[3][e]);
            }
        }
        #pragma unroll
        for (int i = 0; i < 4; ++i) {
            float4 lo = {vo[i][0], vo[i][1], vo[i][2], vo[i][3]};
            float4 hi = {vo[i][4], vo[i][5], vo[i][6], vo[i][7]};
            size_t off = base + (size_t)(ti * 4 + i) * 128 + te * 8;
            *(float4*)(vb + off)     = lo;
            *(float4*)(vb + off + 4) = hi;
        }
    }
}

// =====================================================================
// Kernel 4: scan — MFMA split-bf16. grid 256 = 16 bh x 16 e-groups(8),
// 256 thr (4 waves). Wave w: c-tile w (M1/M2), dk-tiles 2w,2w+1 (M3 C = S).
// S master in f32 C-frags; published hi/lo bf16 to LDS each chunk.
// =====================================================================
__launch_bounds__(256, 1)
__global__ void scan_kernel(const unsigned short* __restrict__ khi,
                            const unsigned short* __restrict__ klo,
                            const float* __restrict__ vpr,
                            const unsigned short* __restrict__ kcdhi,
                            const unsigned short* __restrict__ kcdlo,
                            const unsigned short* __restrict__ att,
                            const float* __restrict__ decay,
                            unsigned short* __restrict__ obuf) {
    __shared__ char SH[4096];   // S hi  [e:16][dk:128] bf16, unit-swizzled
    __shared__ char SL[4096];   // S lo
    __shared__ char VH[2048];   // vnew hi [e:16][c:64]
    __shared__ char VL[2048];   // vnew lo

    int bid = blockIdx.x;
    int bh = bid >> 4, eg = bid & 15, e0 = eg * 8;
    int tid = threadIdx.x;
    int w = tid >> 6, l = tid & 63, lr = l & 15, lk = l >> 4;
    float dec = decay[bh & 7];
    float sg = 1.0f / (1.0f + expf(-dec));
    float lg = logf(sg);
    float g64 = expf(64.f * lg);
    float dev4[4];
    #pragma unroll
    for (int r = 0; r < 4; ++r) dev4[r] = expf((float)(w * 16 + lk * 4 + r + 1) * lg);
    float gdw[2][8];
    #pragma unroll
    for (int ks2 = 0; ks2 < 2; ++ks2)
        #pragma unroll
        for (int j = 0; j < 8; ++j)
            gdw[ks2][j] = expf((float)(63 - (ks2 * 32 + lk * 8 + j)) * lg);

    f32x4 Sacc[2];
    #pragma unroll
    for (int t = 0; t < 2; ++t) Sacc[t] = (f32x4){0.f, 0.f, 0.f, 0.f};

    for (int cn = 0; cn < N_; ++cn) {
        size_t base  = ((size_t)bh * N_ + cn) * 8192;
        size_t abase = ((size_t)bh * N_ + cn) * 4096;

        // ---- early global loads (A-fragments + v' C-init) ----
        bf16x8 cdH[4], cdL[4], kH[4], kL[4];
        #pragma unroll
        for (int ks = 0; ks < 4; ++ks) {
            size_t off = base + (size_t)(w * 16 + lr) * 128 + ks * 32 + lk * 8;
            cdH[ks] = *(const bf16x8*)(kcdhi + off);
            cdL[ks] = *(const bf16x8*)(kcdlo + off);
            kH[ks]  = *(const bf16x8*)(khi + off);
            kL[ks]  = *(const bf16x8*)(klo + off);
        }
        bf16x8 atA[2];
        #pragma unroll
        for (int ks2 = 0; ks2 < 2; ++ks2)
            atA[ks2] = *(const bf16x8*)(att + abase + (size_t)(w * 16 + lr) * 64 + ks2 * 32 + lk * 8);
        f32x4 vn;
        #pragma unroll
        for (int r = 0; r < 4; ++r)
            vn[r] = vpr[base + (size_t)(w * 16 + lk * 4 + r) * 128 + e0 + lr];

        // ---- publish S hi/lo to LDS ----
        #pragma unroll
        for (int t = 0; t < 2; ++t) {
            u16x4 h4, l4;
            #pragma unroll
            for (int r = 0; r < 4; ++r) {
                unsigned short hv = f2bf(Sacc[t][r]);
                h4[r] = hv;
                l4[r] = f2bf(Sacc[t][r] - bf2f(hv));
            }
            int unit = w * 4 + t * 2 + (lk >> 1);
            int off = lr * 256 + ((unit ^ (lr & 7)) << 4) + ((lk & 1) << 3);
            *(u16x4*)(SH + off) = h4;
            *(u16x4*)(SL + off) = l4;
        }
        __syncthreads();   // #1: S visible

        // ---- S B-fragments ----
        bf16x8 BH[4], BL[4];
        #pragma unroll
        for (int ks = 0; ks < 4; ++ks) {
            int off = lr * 256 + (((ks * 4 + lk) ^ (lr & 7)) << 4);
            BH[ks] = *(const bf16x8*)(SH + off);
            BL[ks] = *(const bf16x8*)(SL + off);
        }
        // ---- M1: vnew = v' + (-kcd)@S ----
        #pragma unroll
        for (int ks = 0; ks < 4; ++ks) {
            vn = __builtin_amdgcn_mfma_f32_16x16x32_bf16(cdH[ks], BH[ks], vn, 0, 0, 0);
            vn = __builtin_amdgcn_mfma_f32_16x16x32_bf16(cdH[ks], BL[ks], vn, 0, 0, 0);
            vn = __builtin_amdgcn_mfma_f32_16x16x32_bf16(cdL[ks], BH[ks], vn, 0, 0, 0);
        }
        // ---- publish vnew hi/lo ----
        {
            u16x4 h4, l4;
            #pragma unroll
            for (int r = 0; r < 4; ++r) {
                unsigned short hv = f2bf(vn[r]);
                h4[r] = hv;
                l4[r] = f2bf(vn[r] - bf2f(hv));
            }
            int cu = w * 2 + (lk >> 1);
            int off = lr * 128 + ((cu ^ (lr & 7)) << 4) + ((lk & 1) << 3);
            *(u16x4*)(VH + off) = h4;
            *(u16x4*)(VL + off) = l4;
        }
        __syncthreads();   // #2: vnew visible

        // ---- vnew B-fragments ----
        bf16x8 VHf[2], VLf[2];
        #pragma unroll
        for (int ks2 = 0; ks2 < 2; ++ks2) {
            int off = lr * 128 + (((ks2 * 4 + lk) ^ (lr & 7)) << 4);
            VHf[ks2] = *(const bf16x8*)(VH + off);
            VLf[ks2] = *(const bf16x8*)(VL + off);
        }
        // ---- M2a: o = k@S ----
        f32x4 oacc = (f32x4){0.f, 0.f, 0.f, 0.f};
        #pragma unroll
        for (int ks = 0; ks < 4; ++ks) {
            oacc = __builtin_amdgcn_mfma_f32_16x16x32_bf16(kH[ks], BH[ks], oacc, 0, 0, 0);
            oacc = __builtin_amdgcn_mfma_f32_16x16x32_bf16(kH[ks], BL[ks], oacc, 0, 0, 0);
            oacc = __builtin_amdgcn_mfma_f32_16x16x32_bf16(kL[ks], BH[ks], oacc, 0, 0, 0);
        }
        #pragma unroll
        for (int r = 0; r < 4; ++r) oacc[r] *= dev4[r];
        // ---- M2b: o += att@vnew ----
        #pragma unroll
        for (int ks2 = 0; ks2 < 2; ++ks2) {
            oacc = __builtin_amdgcn_mfma_f32_16x16x32_bf16(atA[ks2], VHf[ks2], oacc, 0, 0, 0);
            oacc = __builtin_amdgcn_mfma_f32_16x16x32_bf16(atA[ks2], VLf[ks2], oacc, 0, 0, 0);
        }
        // ---- store o (bf16, valid e-cols only) ----
        if (lr < 8) {
            size_t ob = ((size_t)bh * T_ + (size_t)cn * 64) * 128 + e0 + lr;
            #pragma unroll
            for (int r = 0; r < 4; ++r)
                obuf[ob + (size_t)(w * 16 + lk * 4 + r) * 128] = f2bf(oacc[r]);
        }
        // ---- M3: S = g64*S + kdw^T @ vnew ----
        #pragma unroll
        for (int t = 0; t < 2; ++t) {
            #pragma unroll
            for (int r = 0; r < 4; ++r) Sacc[t][r] *= g64;
            bf16x8 aH2[2], aL2[2];
            #pragma unroll
            for (int ks2 = 0; ks2 < 2; ++ks2) {
                #pragma unroll
                for (int j = 0; j < 8; ++j) {
                    int c = ks2 * 32 + lk * 8 + j;
                    size_t ko = base + (size_t)c * 128 + (w * 2 + t) * 16 + lr;
                    float val = (bf2f(khi[ko]) + bf2f(klo[ko])) * gdw[ks2][j];
                    unsigned short hv = f2bf(val);
                    aH2[ks2][j] = (short)hv;
                    aL2[ks2][j] = (short)f2bf(val - bf2f(hv));
                }
            }
            #pragma unroll
            for (int ks2 = 0; ks2 < 2; ++ks2) {
                Sacc[t] = __builtin_amdgcn_mfma_f32_16x16x32_bf16(aH2[ks2], VHf[ks2], Sacc[t], 0, 0, 0);
                Sacc[t] = __builtin_amdgcn_mfma_f32_16x16x32_bf16(aH2[ks2], VLf[ks2], Sacc[t], 0, 0, 0);
                Sacc[t] = __builtin_amdgcn_mfma_f32_16x16x32_bf16(aL2[ks2], VHf[ks2], Sacc[t], 0, 0, 0);
            }
        }
        // no barrier needed here: #1 of next iter orders SH writes vs BH reads,
        // #2 orders VH writes vs VHf reads (see race analysis).
    }
}

// =====================================================================
// Kernel 5: final — out = x + o @ W_read^T (o from bf16 obuf).
// =====================================================================
__launch_bounds__(256, 2)
__global__ void final_kernel(const float* __restrict__ X, const float* __restrict__ W,
                             const unsigned short* __restrict__ OB, float* __restrict__ out) {
    __shared__ float As[16][128];
    __shared__ float Bs[16][128];
    int bm = blockIdx.x, bn = blockIdx.y;
    int tid = threadIdx.x;
    int tx = tid & 15, ty = tid >> 4;
    float acc[8][8] = {};
    const float* Bg = W + (size_t)bn * 128 * D_;
    for (int kt = 0; kt < 64; ++kt) {
        int hh = kt >> 3;
        #pragma unroll
        for (int l = 0; l < 2; ++l) {
            int s = tid + l * 256;
            int row = s >> 2, c4 = (s & 3) << 2;
            int m = bm * 128 + row;
            int bb_ = m >> 13, t = m & 8191;
            int e0 = ((kt & 7) << 4) + c4;
            u16x4 av = *(const u16x4*)(OB + (((size_t)(bb_ * H_ + hh) * T_ + t) << 7) + e0);
            float4 bv = *(const float4*)(Bg + (size_t)row * D_ + kt * 16 + c4);
            As[c4 + 0][row] = bf2f(av[0]); As[c4 + 1][row] = bf2f(av[1]);
            As[c4 + 2][row] = bf2f(av[2]); As[c4 + 3][row] = bf2f(av[3]);
            Bs[c4 + 0][row] = bv.x; Bs[c4 + 1][row] = bv.y; Bs[c4 + 2][row] = bv.z; Bs[c4 + 3][row] = bv.w;
        }
        __syncthreads();
        #pragma unroll
        for (int kk = 0; kk < 16; ++kk) {
            float4 a0 = *(const float4*)&As[kk][ty * 8];
            float4 a1 = *(const float4*)&As[kk][ty * 8 + 4];
            float4 b0 = *(const float4*)&Bs[kk][tx * 8];
            float4 b1 = *(const float4*)&Bs[kk][tx * 8 + 4];
            float a[8] = {a0.x, a0.y, a0.z, a0.w, a1.x, a1.y, a1.z, a1.w};
            float bb[8] = {b0.x, b0.y, b0.z, b0.w, b1.x, b1.y, b1.z, b1.w};
            #pragma unroll
            for (int r = 0; r < 8; ++r)
                #pragma unroll
                for (int c = 0; c < 8; ++c)
                    acc[r][c] = fmaf(a[r], bb[c], acc[r][c]);
        }
        __syncthreads();
    }
    int m0 = bm * 128 + ty * 8;
    #pragma unroll
    for (int r = 0; r < 8; ++r) {
        int m = m0 + r;
        size_t xoff = (size_t)m * D_ + bn * 128 + tx * 8;
        float4 x0 = *(const float4*)(X + xoff);
        float4 x1 = *(const float4*)(X + xoff + 4);
        float4 o0 = {x0.x + acc[r][0], x0.y + acc[r][1], x0.z + acc[r][2], x0.w + acc[r][3]};
        float4 o1 = {x1.x + acc[r][4], x1.y + acc[r][5], x1.z + acc[r][6], x1.w + acc[r][7]};
        *(float4*)(out + xoff)     = o0;
        *(float4*)(out + xoff + 4) = o1;
    }
}

// =====================================================================
extern "C" void kernel_launch(void* const* d_in, const int* in_sizes, int n_in,
                              void* d_out, int out_size, void* d_ws, size_t ws_size,
                              hipStream_t stream) {
    const float* X   = (const float*)d_in[0];
    const float* Ww  = (const float*)d_in[1];
    const float* Wr  = (const float*)d_in[2];
    const float* Wb  = (const float*)d_in[3];
    const float* dec = (const float*)d_in[4];

    // workspace layout (bytes), total 252,182,528 (== proven-fitting r3 size)
    char* ws = (char*)d_ws;
    unsigned short* khi  = (unsigned short*)(ws);                 // 32MB
    unsigned short* klo  = (unsigned short*)(ws + 33554432);      // 32MB
    float*          vb   = (float*)(ws + 67108864);               // 64MB  v -> v'
    unsigned short* kcdh = (unsigned short*)(ws + 134217728);     // 32MB
    unsigned short* kcdl = (unsigned short*)(ws + 167772160);     // 32MB
    unsigned short* attn = (unsigned short*)(ws + 201326592);     // 16MB
    float*          beta = (float*)(ws + 218103808);              // 0.5MB
    unsigned short* obuf = (unsigned short*)(ws + 218628096);     // 32MB
    if (ws_size < 252182528ull) return;

    hipFuncSetAttribute((const void*)chunk_kernel, hipFuncAttributeMaxDynamicSharedMemorySize, 65536);

    hipLaunchKernelGGL(prep_kernel, dim3(B_ * T_), dim3(256), 0, stream, X, Wb, khi, klo, beta);
    hipLaunchKernelGGL(vproj_kernel, dim3(128, 8), dim3(256), 0, stream, X, Ww, beta, vb);
    hipLaunchKernelGGL(chunk_kernel, dim3(B_ * H_ * N_), dim3(256), 65536, stream,
                       khi, klo, vb, beta, dec, attn, kcdh, kcdl);
    hipLaunchKernelGGL(scan_kernel, dim3(256), dim3(256), 0, stream,
                       khi, klo, vb, kcdh, kcdl, attn, dec, obuf);
    hipLaunchKernelGGL(final_kernel, dim3(128, 8), dim3(256), 0, stream, X, Wr, obuf, (float*)d_out);
}

// Round 5
// 1561.532 us; speedup vs baseline: 1.4411x; 1.0029x over previous
//
#include <hip/hip_runtime.h>
#include <stdint.h>

#define DEV static __device__ __forceinline__

typedef float          f32x4  __attribute__((ext_vector_type(4)));
typedef short          bf16x8 __attribute__((ext_vector_type(8)));
typedef unsigned short u16x4  __attribute__((ext_vector_type(4)));
typedef unsigned short u16x8  __attribute__((ext_vector_type(8)));

#define B_   2
#define T_   8192
#define D_   1024
#define H_   8
#define HD_  128
#define N_   128   /* chunks per (b,h) */

DEV float dot4(const float4& a, const float4& b) {
    return a.x * b.x + a.y * b.y + a.z * b.z + a.w * b.w;
}
DEV unsigned short f2bf(float f) {
    union { float f; unsigned u; } v; v.f = f;
    unsigned r = (v.u + 0x7fffu + ((v.u >> 16) & 1u)) >> 16;
    return (unsigned short)r;
}
DEV float bf2f(unsigned short u) {
    union { unsigned u; float f; } v; v.u = ((unsigned)u) << 16;
    return v.f;
}
DEV unsigned pk2(unsigned short h, unsigned short l) {
    return (unsigned)h | ((unsigned)l << 16);
}
DEV bf16x8 mk8(unsigned a, unsigned b, unsigned c, unsigned d) {
    union { unsigned u[4]; bf16x8 v; } t;
    t.u[0] = a; t.u[1] = b; t.u[2] = c; t.u[3] = d;
    return t.v;
}
// k-tile LDS swizzle: 16B-unit index XORed with bits of row c (bijective per row)
DEV int swzu(int c, int u) { return u ^ (((c & 7) << 2) | ((c >> 3) & 3)); }

// Swizzled LDS rows of 512B (128 f32); swizzle per 16B unit: unit ^= (row&7).
DEV float4* r512(char* base, int r, int u) {
    return (float4*)(base + (r << 9) + ((u << 4) ^ ((r & 7) << 4)));
}

// =====================================================================
// Kernel 1: prep — L2-normalized k per head -> bf16 hi/lo; beta.
// =====================================================================
__launch_bounds__(256)
__global__ void prep_kernel(const float* __restrict__ X, const float* __restrict__ Wb,
                            unsigned short* __restrict__ khi, unsigned short* __restrict__ klo,
                            float* __restrict__ beta) {
    int bt = blockIdx.x;
    int b = bt >> 13, t = bt & 8191;
    __shared__ float xrow[D_];
    const float* xp = X + (size_t)bt * D_;
    for (int i = threadIdx.x; i < D_; i += 256) xrow[i] = xp[i];
    __syncthreads();
    int w = threadIdx.x >> 6, lane = threadIdx.x & 63;
    for (int h = w; h < H_; h += 4) {
        const float* xh = xrow + h * HD_;
        float a0 = xh[lane], a1 = xh[lane + 64];
        float s = a0 * a0 + a1 * a1;
        #pragma unroll
        for (int off = 32; off > 0; off >>= 1) s += __shfl_xor(s, off);
        float rn = 1.0f / fmaxf(sqrtf(s), 1e-12f);
        const float* wbh = Wb + (size_t)h * D_;
        float bs = 0.f;
        for (int i = lane; i < D_; i += 64) bs += xrow[i] * wbh[i];
        #pragma unroll
        for (int off = 32; off > 0; off >>= 1) bs += __shfl_xor(bs, off);
        float bet = 1.0f / (1.0f + expf(-bs));
        size_t kbase = ((size_t)(b * H_ + h) * T_ + t) * HD_;
        float x0 = a0 * rn, x1 = a1 * rn;
        unsigned short h0 = f2bf(x0), h1 = f2bf(x1);
        khi[kbase + lane]      = h0;
        khi[kbase + lane + 64] = h1;
        klo[kbase + lane]      = f2bf(x0 - bf2f(h0));
        klo[kbase + lane + 64] = f2bf(x1 - bf2f(h1));
        if (lane == 0) beta[(size_t)(b * H_ + h) * T_ + t] = bet;
    }
}

// =====================================================================
// Kernel 2: vproj — v = beta * (x @ W_write^T) -> f32 [bh][t][d]
// =====================================================================
__launch_bounds__(256, 2)
__global__ void vproj_kernel(const float* __restrict__ X, const float* __restrict__ W,
                             const float* __restrict__ beta, float* __restrict__ vb) {
    __shared__ float As[16][128];
    __shared__ float Bs[16][128];
    int bm = blockIdx.x, bn = blockIdx.y;
    int tid = threadIdx.x;
    int tx = tid & 15, ty = tid >> 4;
    float acc[8][8] = {};
    const float* Ag = X + (size_t)bm * 128 * D_;
    const float* Bg = W + (size_t)bn * 128 * D_;
    for (int kt = 0; kt < 64; ++kt) {
        #pragma unroll
        for (int l = 0; l < 2; ++l) {
            int s = tid + l * 256;
            int row = s >> 2, c4 = (s & 3) << 2;
            float4 av = *(const float4*)(Ag + (size_t)row * D_ + kt * 16 + c4);
            float4 bv = *(const float4*)(Bg + (size_t)row * D_ + kt * 16 + c4);
            As[c4 + 0][row] = av.x; As[c4 + 1][row] = av.y; As[c4 + 2][row] = av.z; As[c4 + 3][row] = av.w;
            Bs[c4 + 0][row] = bv.x; Bs[c4 + 1][row] = bv.y; Bs[c4 + 2][row] = bv.z; Bs[c4 + 3][row] = bv.w;
        }
        __syncthreads();
        #pragma unroll
        for (int kk = 0; kk < 16; ++kk) {
            float4 a0 = *(const float4*)&As[kk][ty * 8];
            float4 a1 = *(const float4*)&As[kk][ty * 8 + 4];
            float4 b0 = *(const float4*)&Bs[kk][tx * 8];
            float4 b1 = *(const float4*)&Bs[kk][tx * 8 + 4];
            float a[8] = {a0.x, a0.y, a0.z, a0.w, a1.x, a1.y, a1.z, a1.w};
            float bb[8] = {b0.x, b0.y, b0.z, b0.w, b1.x, b1.y, b1.z, b1.w};
            #pragma unroll
            for (int r = 0; r < 8; ++r)
                #pragma unroll
                for (int c = 0; c < 8; ++c)
                    acc[r][c] = fmaf(a[r], bb[c], acc[r][c]);
        }
        __syncthreads();
    }
    int m0 = bm * 128 + ty * 8;
    #pragma unroll
    for (int r = 0; r < 8; ++r) {
        int m = m0 + r;
        int bb_ = m >> 13, t = m & 8191;
        float bet = beta[(size_t)(bb_ * H_ + bn) * T_ + t];
        size_t ob = ((size_t)(bb_ * H_ + bn) * T_ + t) * HD_ + tx * 8;
        float4 o0 = {acc[r][0] * bet, acc[r][1] * bet, acc[r][2] * bet, acc[r][3] * bet};
        float4 o1 = {acc[r][4] * bet, acc[r][5] * bet, acc[r][6] * bet, acc[r][7] * bet};
        *(float4*)(vb + ob)     = o0;
        *(float4*)(vb + ob + 4) = o1;
    }
}

// =====================================================================
// Kernel 3: chunk — dots, attn(bf16), M, A=M^{-1},
//   kcd-negated (bf16 hi/lo), v' = A@v (f32 in place).
// =====================================================================
__launch_bounds__(256, 2)
__global__ void chunk_kernel(const unsigned short* __restrict__ khi,
                             const unsigned short* __restrict__ klo,
                             float* __restrict__ vb,
                             const float* __restrict__ beta_g,
                             const float* __restrict__ decay,
                             unsigned short* __restrict__ attn_g,
                             unsigned short* __restrict__ kcdhi_g,
                             unsigned short* __restrict__ kcdlo_g) {
    extern __shared__ char cs[];
    char*  sk = cs;                      // [64][128] f32 swz (32KB); later reused for v
    float* sa = (float*)(cs + 32768);    // [64][64] A
    float* sm = (float*)(cs + 49152);    // [64][64] M
    __shared__ float sb[64];
    __shared__ float swgt[64];

    int cid = blockIdx.x;
    int bh = cid >> 7, cn = cid & 127;
    int h = bh & 7;
    int tid = threadIdx.x;
    float dec = decay[h];
    float sg = 1.0f / (1.0f + expf(-dec));
    float lg = logf(sg);
    size_t base = (size_t)cid * 8192;

    #pragma unroll
    for (int lq = 0; lq < 4; ++lq) {
        int f = tid + lq * 256;
        int c = f >> 4, u0 = (f & 15) << 1;
        u16x8 hh = *(const u16x8*)(khi + base + (size_t)f * 8);
        u16x8 ll = *(const u16x8*)(klo + base + (size_t)f * 8);
        float4 v0 = {bf2f(hh[0]) + bf2f(ll[0]), bf2f(hh[1]) + bf2f(ll[1]),
                     bf2f(hh[2]) + bf2f(ll[2]), bf2f(hh[3]) + bf2f(ll[3])};
        float4 v1 = {bf2f(hh[4]) + bf2f(ll[4]), bf2f(hh[5]) + bf2f(ll[5]),
                     bf2f(hh[6]) + bf2f(ll[6]), bf2f(hh[7]) + bf2f(ll[7])};
        *r512(sk, c, u0)     = v0;
        *r512(sk, c, u0 + 1) = v1;
    }
    if (tid < 64) {
        float bv = beta_g[(size_t)bh * T_ + cn * 64 + tid];
        sb[tid] = bv;
        swgt[tid] = bv * expf((float)(tid + 1) * lg);
    }
    __syncthreads();

    int bi = tid >> 4, bj = tid & 15;
    float dacc[4][4] = {};
    for (int u = 0; u < 32; ++u) {
        float4 ka[4], kc[4];
        #pragma unroll
        for (int i = 0; i < 4; ++i) ka[i] = *r512(sk, bi * 4 + i, u);
        #pragma unroll
        for (int j = 0; j < 4; ++j) kc[j] = *r512(sk, bj + 16 * j, u);
        #pragma unroll
        for (int i = 0; i < 4; ++i)
            #pragma unroll
            for (int j = 0; j < 4; ++j)
                dacc[i][j] += dot4(ka[i], kc[j]);
    }
    size_t abase = (size_t)cid * 4096;
    #pragma unroll
    for (int i = 0; i < 4; ++i) {
        int gi = bi * 4 + i;
        #pragma unroll
        for (int j = 0; j < 4; ++j) {
            int gj = bj + 16 * j;
            float dv = dacc[i][j];
            float dfac = expf((float)(gi - gj) * lg);
            attn_g[abase + (size_t)gi * 64 + gj] = (gi >= gj) ? f2bf(dv * dfac) : (unsigned short)0;
            sm[gi * 64 + gj] = (gj < gi) ? sb[gi] * dv * dfac : ((gi == gj) ? 1.f : 0.f);
        }
    }
    __syncthreads();

    if (tid < 64) {
        int j = tid;
        for (int i = 0; i < j; ++i) sa[i * 64 + j] = 0.f;
        sa[j * 64 + j] = 1.f;
        for (int i = j + 1; i < 64; ++i) {
            float s = 0.f;
            for (int p = j; p < i; ++p) s += sm[i * 64 + p] * sa[p * 64 + j];
            sa[i * 64 + j] = -s;
        }
    }
    __syncthreads();

    int ti = tid >> 4, te = tid & 15;
    {
        float ko[4][8] = {};
        for (int p = 0; p < 64; ++p) {
            float w = swgt[p];
            float4 k0 = *r512(sk, p, te * 2);
            float4 k1 = *r512(sk, p, te * 2 + 1);
            float kv[8] = {k0.x, k0.y, k0.z, k0.w, k1.x, k1.y, k1.z, k1.w};
            float a0 = sa[(ti * 4 + 0) * 64 + p] * w;
            float a1 = sa[(ti * 4 + 1) * 64 + p] * w;
            float a2 = sa[(ti * 4 + 2) * 64 + p] * w;
            float a3 = sa[(ti * 4 + 3) * 64 + p] * w;
            #pragma unroll
            for (int e = 0; e < 8; ++e) {
                ko[0][e] = fmaf(a0, kv[e], ko[0][e]);
                ko[1][e] = fmaf(a1, kv[e], ko[1][e]);
                ko[2][e] = fmaf(a2, kv[e], ko[2][e]);
                ko[3][e] = fmaf(a3, kv[e], ko[3][e]);
            }
        }
        #pragma unroll
        for (int i = 0; i < 4; ++i) {
            u16x8 hh, ll;
            #pragma unroll
            for (int e = 0; e < 8; ++e) {
                float t = -ko[i][e];
                unsigned short hv = f2bf(t);
                hh[e] = hv;
                ll[e] = f2bf(t - bf2f(hv));
            }
            size_t off = base + (size_t)(ti * 4 + i) * 128 + te * 8;
            *(u16x8*)(kcdhi_g + off) = hh;
            *(u16x8*)(kcdlo_g + off) = ll;
        }
    }
    __syncthreads();

    #pragma unroll
    for (int lq = 0; lq < 8; ++lq) {
        int f = tid + lq * 256;
        int r = f >> 5, u = f & 31;
        *r512(sk, r, u) = ((const float4*)(vb + base))[f];
    }
    __syncthreads();

    {
        float vo[4][8] = {};
        for (int p = 0; p < 64; ++p) {
            float4 v0 = *r512(sk, p, te * 2);
            float4 v1 = *r512(sk, p, te * 2 + 1);
            float vv[8] = {v0.x, v0.y, v0.z, v0.w, v1.x, v1.y, v1.z, v1.w};
            float a0 = sa[(ti * 4 + 0) * 64 + p];
            float a1 = sa[(ti * 4 + 1) * 64 + p];
            float a2 = sa[(ti * 4 + 2) * 64 + p];
            float a3 = sa[(ti * 4 + 3) * 64 + p];
            #pragma unroll
            for (int e = 0; e < 8; ++e) {
                vo[0][e] = fmaf(a0, vv[e], vo[0][e]);
                vo[1][e] = fmaf(a1, vv[e], vo[1][e]);
                vo[2][e] = fmaf(a2, vv[e], vo[2][e]);
                vo[3][e] = fmaf(a3, vv[e], vo[3][e]);
            }
        }
        #pragma unroll
        for (int i = 0; i < 4; ++i) {
            float4 lo = {vo[i][0], vo[i][1], vo[i][2], vo[i][3]};
            float4 hi = {vo[i][4], vo[i][5], vo[i][6], vo[i][7]};
            size_t off = base + (size_t)(ti * 4 + i) * 128 + te * 8;
            *(float4*)(vb + off)     = lo;
            *(float4*)(vb + off + 4) = hi;
        }
    }
}

// =====================================================================
// Kernel 4: scan v2 — MFMA split-bf16, LDS-staged packed k for the
// transpose fragments, software-pipelined global loads, split chains.
// grid 256 = (16 bh x 16 e-groups, XCD-swizzled), 256 thr, dyn LDS 80KB.
// =====================================================================
__launch_bounds__(256, 1)
__global__ void scan_kernel(const unsigned short* __restrict__ khi,
                            const unsigned short* __restrict__ klo,
                            const float* __restrict__ vpr,
                            const unsigned short* __restrict__ kcdhi,
                            const unsigned short* __restrict__ kcdlo,
                            const unsigned short* __restrict__ att,
                            const float* __restrict__ decay,
                            unsigned short* __restrict__ obuf) {
    extern __shared__ char ls[];
    char* KP = ls;               // 2 x [c:64][dk-u32:128] packed hi|lo<<16, swz; 2x32KB
    char* SH = ls + 65536;       // S^T hi [e:16][dk:128] bf16, 4KB
    char* SL = ls + 69632;
    char* VH = ls + 73728;       // vnew^T hi [e:16][c:64] bf16, 2KB
    char* VL = ls + 75776;
    char* WH = ls + 77824;       // vnew^T * gamma^{63-c} hi
    char* WL = ls + 79872;       // total 81920

    int bid = blockIdx.x;
    int bh = (bid >> 1) & 15;                    // siblings share XCD-L2
    int eg = ((bid >> 5) << 1) | (bid & 1);
    int e0 = eg * 8;
    int tid = threadIdx.x;
    int w = tid >> 6, l = tid & 63, lr = l & 15, lk = l >> 4;
    float dec = decay[bh & 7];
    float sg = 1.0f / (1.0f + expf(-dec));
    float lg = logf(sg);
    float g64 = expf(64.f * lg);
    float dev4[4], gw4[4];
    #pragma unroll
    for (int r = 0; r < 4; ++r) {
        int c = w * 16 + lk * 4 + r;
        dev4[r] = expf((float)(c + 1) * lg);
        gw4[r]  = expf((float)(63 - c) * lg);
    }

    f32x4 Sacc[2];
    #pragma unroll
    for (int t = 0; t < 2; ++t) Sacc[t] = (f32x4){0.f, 0.f, 0.f, 0.f};

    // ---- persistent per-chunk input regs (prefetched one chunk ahead) ----
    u16x4 sh_[8], sl_[8];
    bf16x8 cdH[4], cdL[4], khH[4], khL[4], atA[2];
    f32x4 vnA;

    // prologue: load chunk 0
    {
        size_t nb = (size_t)bh * N_ * 8192;
        size_t na = (size_t)bh * N_ * 4096;
        #pragma unroll
        for (int q = 0; q < 8; ++q) {
            int idx = tid + q * 256;
            sh_[q] = *(const u16x4*)(khi + nb + (size_t)idx * 4);
            sl_[q] = *(const u16x4*)(klo + nb + (size_t)idx * 4);
        }
        #pragma unroll
        for (int ks = 0; ks < 4; ++ks) {
            size_t off = nb + (size_t)(w * 16 + lr) * 128 + ks * 32 + lk * 8;
            cdH[ks] = *(const bf16x8*)(kcdhi + off);
            cdL[ks] = *(const bf16x8*)(kcdlo + off);
            khH[ks] = *(const bf16x8*)(khi + off);
            khL[ks] = *(const bf16x8*)(klo + off);
        }
        #pragma unroll
        for (int ks2 = 0; ks2 < 2; ++ks2)
            atA[ks2] = *(const bf16x8*)(att + na + (size_t)(w * 16 + lr) * 64 + ks2 * 32 + lk * 8);
        #pragma unroll
        for (int r = 0; r < 4; ++r)
            vnA[r] = vpr[nb + (size_t)(w * 16 + lk * 4 + r) * 128 + e0 + lr];
        // stage chunk 0 -> KP[0]
        #pragma unroll
        for (int q = 0; q < 8; ++q) {
            int idx = tid + q * 256;
            int c = idx >> 5, un = idx & 31;
            uint4 pkd = {pk2(sh_[q][0], sl_[q][0]), pk2(sh_[q][1], sl_[q][1]),
                         pk2(sh_[q][2], sl_[q][2]), pk2(sh_[q][3], sl_[q][3])};
            *(uint4*)(KP + c * 512 + (swzu(c, un) << 4)) = pkd;
        }
    }

    for (int cn = 0; cn < N_; ++cn) {
        const char* KPc = KP + (cn & 1) * 32768;

        // ---- publish S hi/lo ----
        #pragma unroll
        for (int t = 0; t < 2; ++t) {
            u16x4 h4, l4;
            #pragma unroll
            for (int r = 0; r < 4; ++r) {
                unsigned short hv = f2bf(Sacc[t][r]);
                h4[r] = hv;
                l4[r] = f2bf(Sacc[t][r] - bf2f(hv));
            }
            int unit = w * 4 + t * 2 + (lk >> 1);
            int off = lr * 256 + ((unit ^ (lr & 7)) << 4) + ((lk & 1) << 3);
            *(u16x4*)(SH + off) = h4;
            *(u16x4*)(SL + off) = l4;
        }
        __syncthreads();   // #1: S + KP[cur] ready

        // ---- S B-fragments ----
        bf16x8 BH[4], BL[4];
        #pragma unroll
        for (int ks = 0; ks < 4; ++ks) {
            int off = lr * 256 + (((ks * 4 + lk) ^ (lr & 7)) << 4);
            BH[ks] = *(const bf16x8*)(SH + off);
            BL[ks] = *(const bf16x8*)(SL + off);
        }
        // ---- M1 (vnew) + M2a (k@S) : 4 independent chains ----
        f32x4 vn = vnA, vn2 = (f32x4){0.f, 0.f, 0.f, 0.f};
        f32x4 oacc = (f32x4){0.f, 0.f, 0.f, 0.f}, oacc2 = oacc;
        #pragma unroll
        for (int ks = 0; ks < 4; ++ks) {
            if (ks < 2) {
                vn = __builtin_amdgcn_mfma_f32_16x16x32_bf16(cdH[ks], BH[ks], vn, 0, 0, 0);
                vn = __builtin_amdgcn_mfma_f32_16x16x32_bf16(cdH[ks], BL[ks], vn, 0, 0, 0);
                vn = __builtin_amdgcn_mfma_f32_16x16x32_bf16(cdL[ks], BH[ks], vn, 0, 0, 0);
                oacc = __builtin_amdgcn_mfma_f32_16x16x32_bf16(khH[ks], BH[ks], oacc, 0, 0, 0);
                oacc = __builtin_amdgcn_mfma_f32_16x16x32_bf16(khH[ks], BL[ks], oacc, 0, 0, 0);
                oacc = __builtin_amdgcn_mfma_f32_16x16x32_bf16(khL[ks], BH[ks], oacc, 0, 0, 0);
            } else {
                vn2 = __builtin_amdgcn_mfma_f32_16x16x32_bf16(cdH[ks], BH[ks], vn2, 0, 0, 0);
                vn2 = __builtin_amdgcn_mfma_f32_16x16x32_bf16(cdH[ks], BL[ks], vn2, 0, 0, 0);
                vn2 = __builtin_amdgcn_mfma_f32_16x16x32_bf16(cdL[ks], BH[ks], vn2, 0, 0, 0);
                oacc2 = __builtin_amdgcn_mfma_f32_16x16x32_bf16(khH[ks], BH[ks], oacc2, 0, 0, 0);
                oacc2 = __builtin_amdgcn_mfma_f32_16x16x32_bf16(khH[ks], BL[ks], oacc2, 0, 0, 0);
                oacc2 = __builtin_amdgcn_mfma_f32_16x16x32_bf16(khL[ks], BH[ks], oacc2, 0, 0, 0);
            }
        }
        // ---- publish vnew (plain + gamma-scaled) hi/lo ----
        {
            u16x4 h4, l4, wh4, wl4;
            #pragma unroll
            for (int r = 0; r < 4; ++r) {
                float vv = vn[r] + vn2[r];
                unsigned short hv = f2bf(vv);
                h4[r] = hv; l4[r] = f2bf(vv - bf2f(hv));
                float wv = vv * gw4[r];
                unsigned short wh = f2bf(wv);
                wh4[r] = wh; wl4[r] = f2bf(wv - bf2f(wh));
            }
            int cu = w * 2 + (lk >> 1);
            int off = lr * 128 + ((cu ^ (lr & 7)) << 4) + ((lk & 1) << 3);
            *(u16x4*)(VH + off) = h4;  *(u16x4*)(VL + off) = l4;
            *(u16x4*)(WH + off) = wh4; *(u16x4*)(WL + off) = wl4;
        }
        __syncthreads();   // #2: vnew visible

        // ---- vnew/W B-fragments ----
        bf16x8 VHf[2], VLf[2], WHf[2], WLf[2];
        #pragma unroll
        for (int ks2 = 0; ks2 < 2; ++ks2) {
            int off = lr * 128 + (((ks2 * 4 + lk) ^ (lr & 7)) << 4);
            VHf[ks2] = *(const bf16x8*)(VH + off);
            VLf[ks2] = *(const bf16x8*)(VL + off);
            WHf[ks2] = *(const bf16x8*)(WH + off);
            WLf[ks2] = *(const bf16x8*)(WL + off);
        }
        // ---- M2b: o = dev*(k@S) + att@vnew ----
        f32x4 om;
        #pragma unroll
        for (int r = 0; r < 4; ++r) om[r] = (oacc[r] + oacc2[r]) * dev4[r];
        #pragma unroll
        for (int ks2 = 0; ks2 < 2; ++ks2) {
            om = __builtin_amdgcn_mfma_f32_16x16x32_bf16(atA[ks2], VHf[ks2], om, 0, 0, 0);
            om = __builtin_amdgcn_mfma_f32_16x16x32_bf16(atA[ks2], VLf[ks2], om, 0, 0, 0);
        }
        if (lr < 8) {
            size_t ob = ((size_t)bh * T_ + (size_t)cn * 64) * 128 + e0 + lr;
            #pragma unroll
            for (int r = 0; r < 4; ++r)
                obuf[ob + (size_t)(w * 16 + lk * 4 + r) * 128] = f2bf(om[r]);
        }

        // ---- prefetch chunk cn+1 (hidden under M3) ----
        if (cn + 1 < N_) {
            size_t nb = ((size_t)bh * N_ + cn + 1) * 8192;
            size_t na = ((size_t)bh * N_ + cn + 1) * 4096;
            #pragma unroll
            for (int q = 0; q < 8; ++q) {
                int idx = tid + q * 256;
                sh_[q] = *(const u16x4*)(khi + nb + (size_t)idx * 4);
                sl_[q] = *(const u16x4*)(klo + nb + (size_t)idx * 4);
            }
            #pragma unroll
            for (int ks = 0; ks < 4; ++ks) {
                size_t off = nb + (size_t)(w * 16 + lr) * 128 + ks * 32 + lk * 8;
                cdH[ks] = *(const bf16x8*)(kcdhi + off);
                cdL[ks] = *(const bf16x8*)(kcdlo + off);
                khH[ks] = *(const bf16x8*)(khi + off);
                khL[ks] = *(const bf16x8*)(klo + off);
            }
            #pragma unroll
            for (int ks2 = 0; ks2 < 2; ++ks2)
                atA[ks2] = *(const bf16x8*)(att + na + (size_t)(w * 16 + lr) * 64 + ks2 * 32 + lk * 8);
            #pragma unroll
            for (int r = 0; r < 4; ++r)
                vnA[r] = vpr[nb + (size_t)(w * 16 + lk * 4 + r) * 128 + e0 + lr];
        }

        // ---- M3: S = g64*S + k^T @ (gamma-scaled vnew) ----
        #pragma unroll
        for (int t = 0; t < 2; ++t) {
            #pragma unroll
            for (int r = 0; r < 4; ++r) Sacc[t][r] *= g64;
            int dk = (w * 2 + t) * 16 + lr;
            int du = dk >> 2, db = (dk & 3) << 2;
            #pragma unroll
            for (int ks2 = 0; ks2 < 2; ++ks2) {
                unsigned uv[8];
                #pragma unroll
                for (int j = 0; j < 8; ++j) {
                    int c = ks2 * 32 + lk * 8 + j;
                    uv[j] = *(const unsigned*)(KPc + c * 512 + (swzu(c, du) << 4) + db);
                }
                bf16x8 tH = mk8((uv[0] & 0xffffu) | (uv[1] << 16), (uv[2] & 0xffffu) | (uv[3] << 16),
                                (uv[4] & 0xffffu) | (uv[5] << 16), (uv[6] & 0xffffu) | (uv[7] << 16));
                bf16x8 tL = mk8((uv[0] >> 16) | (uv[1] & 0xffff0000u), (uv[2] >> 16) | (uv[3] & 0xffff0000u),
                                (uv[4] >> 16) | (uv[5] & 0xffff0000u), (uv[6] >> 16) | (uv[7] & 0xffff0000u));
                Sacc[t] = __builtin_amdgcn_mfma_f32_16x16x32_bf16(tH, WHf[ks2], Sacc[t], 0, 0, 0);
                Sacc[t] = __builtin_amdgcn_mfma_f32_16x16x32_bf16(tH, WLf[ks2], Sacc[t], 0, 0, 0);
                Sacc[t] = __builtin_amdgcn_mfma_f32_16x16x32_bf16(tL, WHf[ks2], Sacc[t], 0, 0, 0);
            }
        }

        // ---- stage chunk cn+1 -> other KP buffer ----
        if (cn + 1 < N_) {
            char* KPn = KP + ((cn + 1) & 1) * 32768;
            #pragma unroll
            for (int q = 0; q < 8; ++q) {
                int idx = tid + q * 256;
                int c = idx >> 5, un = idx & 31;
                uint4 pkd = {pk2(sh_[q][0], sl_[q][0]), pk2(sh_[q][1], sl_[q][1]),
                             pk2(sh_[q][2], sl_[q][2]), pk2(sh_[q][3], sl_[q][3])};
                *(uint4*)(KPn + c * 512 + (swzu(c, un) << 4)) = pkd;
            }
        }
        // next barrier #1 orders staging writes & KP reads
    }
}

// =====================================================================
// Kernel 5: final — out = x + o @ W_read^T (o from bf16 obuf).
// =====================================================================
__launch_bounds__(256, 2)
__global__ void final_kernel(const float* __restrict__ X, const float* __restrict__ W,
                             const unsigned short* __restrict__ OB, float* __restrict__ out) {
    __shared__ float As[16][128];
    __shared__ float Bs[16][128];
    int bm = blockIdx.x, bn = blockIdx.y;
    int tid = threadIdx.x;
    int tx = tid & 15, ty = tid >> 4;
    float acc[8][8] = {};
    const float* Bg = W + (size_t)bn * 128 * D_;
    for (int kt = 0; kt < 64; ++kt) {
        int hh = kt >> 3;
        #pragma unroll
        for (int l = 0; l < 2; ++l) {
            int s = tid + l * 256;
            int row = s >> 2, c4 = (s & 3) << 2;
            int m = bm * 128 + row;
            int bb_ = m >> 13, t = m & 8191;
            int e0 = ((kt & 7) << 4) + c4;
            u16x4 av = *(const u16x4*)(OB + (((size_t)(bb_ * H_ + hh) * T_ + t) << 7) + e0);
            float4 bv = *(const float4*)(Bg + (size_t)row * D_ + kt * 16 + c4);
            As[c4 + 0][row] = bf2f(av[0]); As[c4 + 1][row] = bf2f(av[1]);
            As[c4 + 2][row] = bf2f(av[2]); As[c4 + 3][row] = bf2f(av[3]);
            Bs[c4 + 0][row] = bv.x; Bs[c4 + 1][row] = bv.y; Bs[c4 + 2][row] = bv.z; Bs[c4 + 3][row] = bv.w;
        }
        __syncthreads();
        #pragma unroll
        for (int kk = 0; kk < 16; ++kk) {
            float4 a0 = *(const float4*)&As[kk][ty * 8];
            float4 a1 = *(const float4*)&As[kk][ty * 8 + 4];
            float4 b0 = *(const float4*)&Bs[kk][tx * 8];
            float4 b1 = *(const float4*)&Bs[kk][tx * 8 + 4];
            float a[8] = {a0.x, a0.y, a0.z, a0.w, a1.x, a1.y, a1.z, a1.w};
            float bb[8] = {b0.x, b0.y, b0.z, b0.w, b1.x, b1.y, b1.z, b1.w};
            #pragma unroll
            for (int r = 0; r < 8; ++r)
                #pragma unroll
                for (int c = 0; c < 8; ++c)
                    acc[r][c] = fmaf(a[r], bb[c], acc[r][c]);
        }
        __syncthreads();
    }
    int m0 = bm * 128 + ty * 8;
    #pragma unroll
    for (int r = 0; r < 8; ++r) {
        int m = m0 + r;
        size_t xoff = (size_t)m * D_ + bn * 128 + tx * 8;
        float4 x0 = *(const float4*)(X + xoff);
        float4 x1 = *(const float4*)(X + xoff + 4);
        float4 o0 = {x0.x + acc[r][0], x0.y + acc[r][1], x0.z + acc[r][2], x0.w + acc[r][3]};
        float4 o1 = {x1.x + acc[r][4], x1.y + acc[r][5], x1.z + acc[r][6], x1.w + acc[r][7]};
        *(float4*)(out + xoff)     = o0;
        *(float4*)(out + xoff + 4) = o1;
    }
}

// =====================================================================
extern "C" void kernel_launch(void* const* d_in, const int* in_sizes, int n_in,
                              void* d_out, int out_size, void* d_ws, size_t ws_size,
                              hipStream_t stream) {
    const float* X   = (const float*)d_in[0];
    const float* Ww  = (const float*)d_in[1];
    const float* Wr  = (const float*)d_in[2];
    const float* Wb  = (const float*)d_in[3];
    const float* dec = (const float*)d_in[4];

    // workspace layout (bytes), total 252,182,528 (proven-fitting)
    char* ws = (char*)d_ws;
    unsigned short* khi  = (unsigned short*)(ws);                 // 32MB
    unsigned short* klo  = (unsigned short*)(ws + 33554432);      // 32MB
    float*          vb   = (float*)(ws + 67108864);               // 64MB  v -> v'
    unsigned short* kcdh = (unsigned short*)(ws + 134217728);     // 32MB
    unsigned short* kcdl = (unsigned short*)(ws + 167772160);     // 32MB
    unsigned short* attn = (unsigned short*)(ws + 201326592);     // 16MB
    float*          beta = (float*)(ws + 218103808);              // 0.5MB
    unsigned short* obuf = (unsigned short*)(ws + 218628096);     // 32MB
    if (ws_size < 252182528ull) return;

    hipFuncSetAttribute((const void*)chunk_kernel, hipFuncAttributeMaxDynamicSharedMemorySize, 65536);
    hipFuncSetAttribute((const void*)scan_kernel,  hipFuncAttributeMaxDynamicSharedMemorySize, 81920);

    hipLaunchKernelGGL(prep_kernel, dim3(B_ * T_), dim3(256), 0, stream, X, Wb, khi, klo, beta);
    hipLaunchKernelGGL(vproj_kernel, dim3(128, 8), dim3(256), 0, stream, X, Ww, beta, vb);
    hipLaunchKernelGGL(chunk_kernel, dim3(B_ * H_ * N_), dim3(256), 65536, stream,
                       khi, klo, vb, beta, dec, attn, kcdh, kcdl);
    hipLaunchKernelGGL(scan_kernel, dim3(256), dim3(256), 81920, stream,
                       khi, klo, vb, kcdh, kcdl, attn, dec, obuf);
    hipLaunchKernelGGL(final_kernel, dim3(128, 8), dim3(256), 0, stream, X, Wr, obuf, (float*)d_out);
}

// Round 6
// 1555.868 us; speedup vs baseline: 1.4464x; 1.0036x over previous
//
#include <hip/hip_runtime.h>
#include <stdint.h>

#define DEV static __device__ __forceinline__

typedef float          f32x4  __attribute__((ext_vector_type(4)));
typedef short          bf16x8 __attribute__((ext_vector_type(8)));
typedef unsigned short u16x4  __attribute__((ext_vector_type(4)));
typedef unsigned short u16x8  __attribute__((ext_vector_type(8)));

#define B_   2
#define T_   8192
#define D_   1024
#define H_   8
#define HD_  128
#define N_   128   /* chunks per (b,h) */

DEV float dot4(const float4& a, const float4& b) {
    return a.x * b.x + a.y * b.y + a.z * b.z + a.w * b.w;
}
DEV unsigned short f2bf(float f) {
    union { float f; unsigned u; } v; v.f = f;
    unsigned r = (v.u + 0x7fffu + ((v.u >> 16) & 1u)) >> 16;
    return (unsigned short)r;
}
DEV float bf2f(unsigned short u) {
    union { unsigned u; float f; } v; v.u = ((unsigned)u) << 16;
    return v.f;
}
DEV unsigned pk2(unsigned short h, unsigned short l) {
    return (unsigned)h | ((unsigned)l << 16);
}
DEV bf16x8 mk8(unsigned a, unsigned b, unsigned c, unsigned d) {
    union { unsigned u[4]; bf16x8 v; } t;
    t.u[0] = a; t.u[1] = b; t.u[2] = c; t.u[3] = d;
    return t.v;
}
// k-tile LDS swizzle: 16B-unit index XORed with bits of row c (bijective per row)
DEV int swzu(int c, int u) { return u ^ (((c & 7) << 2) | ((c >> 3) & 3)); }

// Swizzled LDS rows of 512B (128 f32); swizzle per 16B unit: unit ^= (row&7).
DEV float4* r512(char* base, int r, int u) {
    return (float4*)(base + (r << 9) + ((u << 4) ^ ((r & 7) << 4)));
}

// =====================================================================
// Kernel 1: prep — L2-normalized k per head -> bf16 hi/lo; beta.
// =====================================================================
__launch_bounds__(256)
__global__ void prep_kernel(const float* __restrict__ X, const float* __restrict__ Wb,
                            unsigned short* __restrict__ khi, unsigned short* __restrict__ klo,
                            float* __restrict__ beta) {
    int bt = blockIdx.x;
    int b = bt >> 13, t = bt & 8191;
    __shared__ float xrow[D_];
    const float* xp = X + (size_t)bt * D_;
    for (int i = threadIdx.x; i < D_; i += 256) xrow[i] = xp[i];
    __syncthreads();
    int w = threadIdx.x >> 6, lane = threadIdx.x & 63;
    for (int h = w; h < H_; h += 4) {
        const float* xh = xrow + h * HD_;
        float a0 = xh[lane], a1 = xh[lane + 64];
        float s = a0 * a0 + a1 * a1;
        #pragma unroll
        for (int off = 32; off > 0; off >>= 1) s += __shfl_xor(s, off);
        float rn = 1.0f / fmaxf(sqrtf(s), 1e-12f);
        const float* wbh = Wb + (size_t)h * D_;
        float bs = 0.f;
        for (int i = lane; i < D_; i += 64) bs += xrow[i] * wbh[i];
        #pragma unroll
        for (int off = 32; off > 0; off >>= 1) bs += __shfl_xor(bs, off);
        float bet = 1.0f / (1.0f + expf(-bs));
        size_t kbase = ((size_t)(b * H_ + h) * T_ + t) * HD_;
        float x0 = a0 * rn, x1 = a1 * rn;
        unsigned short h0 = f2bf(x0), h1 = f2bf(x1);
        khi[kbase + lane]      = h0;
        khi[kbase + lane + 64] = h1;
        klo[kbase + lane]      = f2bf(x0 - bf2f(h0));
        klo[kbase + lane + 64] = f2bf(x1 - bf2f(h1));
        if (lane == 0) beta[(size_t)(b * H_ + h) * T_ + t] = bet;
    }
}

// =====================================================================
// Kernel 2: vproj — v = beta * (x @ W_write^T) -> f32 [bh][t][d]
// =====================================================================
__launch_bounds__(256, 2)
__global__ void vproj_kernel(const float* __restrict__ X, const float* __restrict__ W,
                             const float* __restrict__ beta, float* __restrict__ vb) {
    __shared__ float As[16][128];
    __shared__ float Bs[16][128];
    int bm = blockIdx.x, bn = blockIdx.y;
    int tid = threadIdx.x;
    int tx = tid & 15, ty = tid >> 4;
    float acc[8][8] = {};
    const float* Ag = X + (size_t)bm * 128 * D_;
    const float* Bg = W + (size_t)bn * 128 * D_;
    for (int kt = 0; kt < 64; ++kt) {
        #pragma unroll
        for (int l = 0; l < 2; ++l) {
            int s = tid + l * 256;
            int row = s >> 2, c4 = (s & 3) << 2;
            float4 av = *(const float4*)(Ag + (size_t)row * D_ + kt * 16 + c4);
            float4 bv = *(const float4*)(Bg + (size_t)row * D_ + kt * 16 + c4);
            As[c4 + 0][row] = av.x; As[c4 + 1][row] = av.y; As[c4 + 2][row] = av.z; As[c4 + 3][row] = av.w;
            Bs[c4 + 0][row] = bv.x; Bs[c4 + 1][row] = bv.y; Bs[c4 + 2][row] = bv.z; Bs[c4 + 3][row] = bv.w;
        }
        __syncthreads();
        #pragma unroll
        for (int kk = 0; kk < 16; ++kk) {
            float4 a0 = *(const float4*)&As[kk][ty * 8];
            float4 a1 = *(const float4*)&As[kk][ty * 8 + 4];
            float4 b0 = *(const float4*)&Bs[kk][tx * 8];
            float4 b1 = *(const float4*)&Bs[kk][tx * 8 + 4];
            float a[8] = {a0.x, a0.y, a0.z, a0.w, a1.x, a1.y, a1.z, a1.w};
            float bb[8] = {b0.x, b0.y, b0.z, b0.w, b1.x, b1.y, b1.z, b1.w};
            #pragma unroll
            for (int r = 0; r < 8; ++r)
                #pragma unroll
                for (int c = 0; c < 8; ++c)
                    acc[r][c] = fmaf(a[r], bb[c], acc[r][c]);
        }
        __syncthreads();
    }
    int m0 = bm * 128 + ty * 8;
    #pragma unroll
    for (int r = 0; r < 8; ++r) {
        int m = m0 + r;
        int bb_ = m >> 13, t = m & 8191;
        float bet = beta[(size_t)(bb_ * H_ + bn) * T_ + t];
        size_t ob = ((size_t)(bb_ * H_ + bn) * T_ + t) * HD_ + tx * 8;
        float4 o0 = {acc[r][0] * bet, acc[r][1] * bet, acc[r][2] * bet, acc[r][3] * bet};
        float4 o1 = {acc[r][4] * bet, acc[r][5] * bet, acc[r][6] * bet, acc[r][7] * bet};
        *(float4*)(vb + ob)     = o0;
        *(float4*)(vb + ob + 4) = o1;
    }
}

// =====================================================================
// Kernel 3: chunk — dots, attn(bf16), M, A=M^{-1},
//   kcd-negated (bf16 hi/lo), v' = A@v (f32 in place).
// =====================================================================
__launch_bounds__(256, 2)
__global__ void chunk_kernel(const unsigned short* __restrict__ khi,
                             const unsigned short* __restrict__ klo,
                             float* __restrict__ vb,
                             const float* __restrict__ beta_g,
                             const float* __restrict__ decay,
                             unsigned short* __restrict__ attn_g,
                             unsigned short* __restrict__ kcdhi_g,
                             unsigned short* __restrict__ kcdlo_g) {
    extern __shared__ char cs[];
    char*  sk = cs;                      // [64][128] f32 swz (32KB); later reused for v
    float* sa = (float*)(cs + 32768);    // [64][64] A
    float* sm = (float*)(cs + 49152);    // [64][64] M
    __shared__ float sb[64];
    __shared__ float swgt[64];

    int cid = blockIdx.x;
    int bh = cid >> 7, cn = cid & 127;
    int h = bh & 7;
    int tid = threadIdx.x;
    float dec = decay[h];
    float sg = 1.0f / (1.0f + expf(-dec));
    float lg = logf(sg);
    size_t base = (size_t)cid * 8192;

    #pragma unroll
    for (int lq = 0; lq < 4; ++lq) {
        int f = tid + lq * 256;
        int c = f >> 4, u0 = (f & 15) << 1;
        u16x8 hh = *(const u16x8*)(khi + base + (size_t)f * 8);
        u16x8 ll = *(const u16x8*)(klo + base + (size_t)f * 8);
        float4 v0 = {bf2f(hh[0]) + bf2f(ll[0]), bf2f(hh[1]) + bf2f(ll[1]),
                     bf2f(hh[2]) + bf2f(ll[2]), bf2f(hh[3]) + bf2f(ll[3])};
        float4 v1 = {bf2f(hh[4]) + bf2f(ll[4]), bf2f(hh[5]) + bf2f(ll[5]),
                     bf2f(hh[6]) + bf2f(ll[6]), bf2f(hh[7]) + bf2f(ll[7])};
        *r512(sk, c, u0)     = v0;
        *r512(sk, c, u0 + 1) = v1;
    }
    if (tid < 64) {
        float bv = beta_g[(size_t)bh * T_ + cn * 64 + tid];
        sb[tid] = bv;
        swgt[tid] = bv * expf((float)(tid + 1) * lg);
    }
    __syncthreads();

    int bi = tid >> 4, bj = tid & 15;
    float dacc[4][4] = {};
    for (int u = 0; u < 32; ++u) {
        float4 ka[4], kc[4];
        #pragma unroll
        for (int i = 0; i < 4; ++i) ka[i] = *r512(sk, bi * 4 + i, u);
        #pragma unroll
        for (int j = 0; j < 4; ++j) kc[j] = *r512(sk, bj + 16 * j, u);
        #pragma unroll
        for (int i = 0; i < 4; ++i)
            #pragma unroll
            for (int j = 0; j < 4; ++j)
                dacc[i][j] += dot4(ka[i], kc[j]);
    }
    size_t abase = (size_t)cid * 4096;
    #pragma unroll
    for (int i = 0; i < 4; ++i) {
        int gi = bi * 4 + i;
        #pragma unroll
        for (int j = 0; j < 4; ++j) {
            int gj = bj + 16 * j;
            float dv = dacc[i][j];
            float dfac = expf((float)(gi - gj) * lg);
            attn_g[abase + (size_t)gi * 64 + gj] = (gi >= gj) ? f2bf(dv * dfac) : (unsigned short)0;
            sm[gi * 64 + gj] = (gj < gi) ? sb[gi] * dv * dfac : ((gi == gj) ? 1.f : 0.f);
        }
    }
    __syncthreads();

    if (tid < 64) {
        int j = tid;
        for (int i = 0; i < j; ++i) sa[i * 64 + j] = 0.f;
        sa[j * 64 + j] = 1.f;
        for (int i = j + 1; i < 64; ++i) {
            float s = 0.f;
            for (int p = j; p < i; ++p) s += sm[i * 64 + p] * sa[p * 64 + j];
            sa[i * 64 + j] = -s;
        }
    }
    __syncthreads();

    int ti = tid >> 4, te = tid & 15;
    {
        float ko[4][8] = {};
        for (int p = 0; p < 64; ++p) {
            float w = swgt[p];
            float4 k0 = *r512(sk, p, te * 2);
            float4 k1 = *r512(sk, p, te * 2 + 1);
            float kv[8] = {k0.x, k0.y, k0.z, k0.w, k1.x, k1.y, k1.z, k1.w};
            float a0 = sa[(ti * 4 + 0) * 64 + p] * w;
            float a1 = sa[(ti * 4 + 1) * 64 + p] * w;
            float a2 = sa[(ti * 4 + 2) * 64 + p] * w;
            float a3 = sa[(ti * 4 + 3) * 64 + p] * w;
            #pragma unroll
            for (int e = 0; e < 8; ++e) {
                ko[0][e] = fmaf(a0, kv[e], ko[0][e]);
                ko[1][e] = fmaf(a1, kv[e], ko[1][e]);
                ko[2][e] = fmaf(a2, kv[e], ko[2][e]);
                ko[3][e] = fmaf(a3, kv[e], ko[3][e]);
            }
        }
        #pragma unroll
        for (int i = 0; i < 4; ++i) {
            u16x8 hh, ll;
            #pragma unroll
            for (int e = 0; e < 8; ++e) {
                float t = -ko[i][e];
                unsigned short hv = f2bf(t);
                hh[e] = hv;
                ll[e] = f2bf(t - bf2f(hv));
            }
            size_t off = base + (size_t)(ti * 4 + i) * 128 + te * 8;
            *(u16x8*)(kcdhi_g + off) = hh;
            *(u16x8*)(kcdlo_g + off) = ll;
        }
    }
    __syncthreads();

    #pragma unroll
    for (int lq = 0; lq < 8; ++lq) {
        int f = tid + lq * 256;
        int r = f >> 5, u = f & 31;
        *r512(sk, r, u) = ((const float4*)(vb + base))[f];
    }
    __syncthreads();

    {
        float vo[4][8] = {};
        for (int p = 0; p < 64; ++p) {
            float4 v0 = *r512(sk, p, te * 2);
            float4 v1 = *r512(sk, p, te * 2 + 1);
            float vv[8] = {v0.x, v0.y, v0.z, v0.w, v1.x, v1.y, v1.z, v1.w};
            float a0 = sa[(ti * 4 + 0) * 64 + p];
            float a1 = sa[(ti * 4 + 1) * 64 + p];
            float a2 = sa[(ti * 4 + 2) * 64 + p];
            float a3 = sa[(ti * 4 + 3) * 64 + p];
            #pragma unroll
            for (int e = 0; e < 8; ++e) {
                vo[0][e] = fmaf(a0, vv[e], vo[0][e]);
                vo[1][e] = fmaf(a1, vv[e], vo[1][e]);
                vo[2][e] = fmaf(a2, vv[e], vo[2][e]);
                vo[3][e] = fmaf(a3, vv[e], vo[3][e]);
            }
        }
        #pragma unroll
        for (int i = 0; i < 4; ++i) {
            float4 lo = {vo[i][0], vo[i][1], vo[i][2], vo[i][3]};
            float4 hi = {vo[i][4], vo[i][5], vo[i][6], vo[i][7]};
            size_t off = base + (size_t)(ti * 4 + i) * 128 + te * 8;
            *(float4*)(vb + off)     = lo;
            *(float4*)(vb + off + 4) = hi;
        }
    }
}

// =====================================================================
// Kernel 4: scan v3 — 8-wave role-split, full 16-wide e-tiles.
// grid 128 = 16 bh x 8 e-strips(16), 512 thr (8 waves), dyn LDS 80KB.
// Waves 0-3 (grp0): M1 (vnew) per c-tile; waves 4-7 (grp1): M2a/M2b (o).
// All 8 waves: M3 S-update, one 16-row dk-tile each (f32 C-frag master).
// =====================================================================
__launch_bounds__(512, 1)
__global__ void scan_kernel(const unsigned short* __restrict__ khi,
                            const unsigned short* __restrict__ klo,
                            const float* __restrict__ vpr,
                            const unsigned short* __restrict__ kcdhi,
                            const unsigned short* __restrict__ kcdlo,
                            const unsigned short* __restrict__ att,
                            const float* __restrict__ decay,
                            unsigned short* __restrict__ obuf) {
    extern __shared__ char ls[];
    char* KP = ls;               // 2 x [c:64][dk-u32:128] packed hi|lo<<16, swz; 2x32KB
    char* SH = ls + 65536;       // S^T hi [e:16][dk:128] bf16, 4KB
    char* SL = ls + 69632;
    char* VH = ls + 73728;       // vnew^T hi [e:16][c:64] bf16, 2KB
    char* VL = ls + 75776;
    char* WH = ls + 77824;       // vnew^T * gamma^{63-c} hi
    char* WL = ls + 79872;       // total 81920

    int bid = blockIdx.x;                 // 0..127
    int h7 = bid & 7;                     // same-h blocks share an XCD
    int strip = (bid >> 3) & 7;
    int bh = ((bid >> 6) << 3) + h7;      // 0..15
    int e0 = strip * 16;
    int tid = threadIdx.x;
    int w = tid >> 6, l = tid & 63, lr = l & 15, lk = l >> 4;
    int grp = w >> 2, cw = w & 3;
    float dec = decay[bh & 7];
    float sg = 1.0f / (1.0f + expf(-dec));
    float lg = logf(sg);
    float g64 = expf(64.f * lg);
    float dev4[4], gw4[4];
    #pragma unroll
    for (int r = 0; r < 4; ++r) {
        int c = cw * 16 + lk * 4 + r;
        dev4[r] = expf((float)(c + 1) * lg);   // used by grp1
        gw4[r]  = expf((float)(63 - c) * lg);  // used by grp0
    }

    f32x4 Sacc = (f32x4){0.f, 0.f, 0.f, 0.f};  // S^T dk-tile w, e cols 0..15

    // persistent per-chunk regs (role-split, prefetched one chunk ahead)
    unsigned sh_[4][4], sl_[4][4];   // staging: 16 u32-pairs worth
    bf16x8 fH[4], fL[4];             // grp0: kcd ; grp1: k
    bf16x8 atA[2];                   // grp1 only
    f32x4 vnA;                       // grp0 only

    // ---- prologue: prefetch + stage chunk 0 ----
    {
        size_t nb = (size_t)bh * N_ * 8192;
        size_t na = (size_t)bh * N_ * 4096;
        #pragma unroll
        for (int q = 0; q < 4; ++q) {
            int idx = tid + q * 512;
            u16x4 hh = *(const u16x4*)(khi + nb + (size_t)idx * 4);
            u16x4 ll = *(const u16x4*)(klo + nb + (size_t)idx * 4);
            #pragma unroll
            for (int j = 0; j < 4; ++j) { sh_[q][j] = hh[j]; sl_[q][j] = ll[j]; }
        }
        if (grp == 0) {
            #pragma unroll
            for (int ks = 0; ks < 4; ++ks) {
                size_t off = nb + (size_t)(cw * 16 + lr) * 128 + ks * 32 + lk * 8;
                fH[ks] = *(const bf16x8*)(kcdhi + off);
                fL[ks] = *(const bf16x8*)(kcdlo + off);
            }
            #pragma unroll
            for (int r = 0; r < 4; ++r)
                vnA[r] = vpr[nb + (size_t)(cw * 16 + lk * 4 + r) * 128 + e0 + lr];
        } else {
            #pragma unroll
            for (int ks = 0; ks < 4; ++ks) {
                size_t off = nb + (size_t)(cw * 16 + lr) * 128 + ks * 32 + lk * 8;
                fH[ks] = *(const bf16x8*)(khi + off);
                fL[ks] = *(const bf16x8*)(klo + off);
            }
            #pragma unroll
            for (int ks2 = 0; ks2 < 2; ++ks2)
                atA[ks2] = *(const bf16x8*)(att + na + (size_t)(cw * 16 + lr) * 64 + ks2 * 32 + lk * 8);
        }
        #pragma unroll
        for (int q = 0; q < 4; ++q) {
            int idx = tid + q * 512;
            int c = idx >> 5, un = idx & 31;
            uint4 pkd = {pk2((unsigned short)sh_[q][0], (unsigned short)sl_[q][0]),
                         pk2((unsigned short)sh_[q][1], (unsigned short)sl_[q][1]),
                         pk2((unsigned short)sh_[q][2], (unsigned short)sl_[q][2]),
                         pk2((unsigned short)sh_[q][3], (unsigned short)sl_[q][3])};
            *(uint4*)(KP + c * 512 + (swzu(c, un) << 4)) = pkd;
        }
    }

    for (int cn = 0; cn < N_; ++cn) {
        const char* KPc = KP + (cn & 1) * 32768;

        // ---- publish S hi/lo (all waves; wave w owns dk rows [16w,16w+16)) ----
        {
            u16x4 h4, l4;
            #pragma unroll
            for (int r = 0; r < 4; ++r) {
                unsigned short hv = f2bf(Sacc[r]);
                h4[r] = hv;
                l4[r] = f2bf(Sacc[r] - bf2f(hv));
            }
            int unit = 2 * w + (lk >> 1);    // 0..15
            int off = lr * 256 + ((unit ^ (lr & 7)) << 4) + ((lk & 1) << 3);
            *(u16x4*)(SH + off) = h4;
            *(u16x4*)(SL + off) = l4;
        }
        __syncthreads();   // bar1: S + KP[cur] ready

        // ---- S B-fragments (e=lr col, dk K-slices) ----
        bf16x8 BH[4], BL[4];
        #pragma unroll
        for (int ks = 0; ks < 4; ++ks) {
            int off = lr * 256 + (((ks * 4 + lk) ^ (lr & 7)) << 4);
            BH[ks] = *(const bf16x8*)(SH + off);
            BL[ks] = *(const bf16x8*)(SL + off);
        }
        f32x4 acc1, acc2;
        if (grp == 0) {
            // ---- M1: vnew = v' + (-kcd)@S, 2 chains ----
            acc1 = vnA; acc2 = (f32x4){0.f, 0.f, 0.f, 0.f};
            __builtin_amdgcn_s_setprio(1);
            #pragma unroll
            for (int ks = 0; ks < 2; ++ks) {
                acc1 = __builtin_amdgcn_mfma_f32_16x16x32_bf16(fH[ks], BH[ks], acc1, 0, 0, 0);
                acc2 = __builtin_amdgcn_mfma_f32_16x16x32_bf16(fH[ks+2], BH[ks+2], acc2, 0, 0, 0);
                acc1 = __builtin_amdgcn_mfma_f32_16x16x32_bf16(fH[ks], BL[ks], acc1, 0, 0, 0);
                acc2 = __builtin_amdgcn_mfma_f32_16x16x32_bf16(fH[ks+2], BL[ks+2], acc2, 0, 0, 0);
                acc1 = __builtin_amdgcn_mfma_f32_16x16x32_bf16(fL[ks], BH[ks], acc1, 0, 0, 0);
                acc2 = __builtin_amdgcn_mfma_f32_16x16x32_bf16(fL[ks+2], BH[ks+2], acc2, 0, 0, 0);
            }
            __builtin_amdgcn_s_setprio(0);
            // ---- publish vnew (plain + gamma-scaled) hi/lo ----
            u16x4 h4, l4, wh4, wl4;
            #pragma unroll
            for (int r = 0; r < 4; ++r) {
                float vv = acc1[r] + acc2[r];
                unsigned short hv = f2bf(vv);
                h4[r] = hv; l4[r] = f2bf(vv - bf2f(hv));
                float wv = vv * gw4[r];
                unsigned short wh = f2bf(wv);
                wh4[r] = wh; wl4[r] = f2bf(wv - bf2f(wh));
            }
            int cu = 2 * cw + (lk >> 1);     // 0..7
            int off = lr * 128 + ((cu ^ (lr & 7)) << 4) + ((lk & 1) << 3);
            *(u16x4*)(VH + off) = h4;  *(u16x4*)(VL + off) = l4;
            *(u16x4*)(WH + off) = wh4; *(u16x4*)(WL + off) = wl4;
        } else {
            // ---- M2a: k@S, 2 chains ----
            acc1 = (f32x4){0.f, 0.f, 0.f, 0.f}; acc2 = acc1;
            __builtin_amdgcn_s_setprio(1);
            #pragma unroll
            for (int ks = 0; ks < 2; ++ks) {
                acc1 = __builtin_amdgcn_mfma_f32_16x16x32_bf16(fH[ks], BH[ks], acc1, 0, 0, 0);
                acc2 = __builtin_amdgcn_mfma_f32_16x16x32_bf16(fH[ks+2], BH[ks+2], acc2, 0, 0, 0);
                acc1 = __builtin_amdgcn_mfma_f32_16x16x32_bf16(fH[ks], BL[ks], acc1, 0, 0, 0);
                acc2 = __builtin_amdgcn_mfma_f32_16x16x32_bf16(fH[ks+2], BL[ks+2], acc2, 0, 0, 0);
                acc1 = __builtin_amdgcn_mfma_f32_16x16x32_bf16(fL[ks], BH[ks], acc1, 0, 0, 0);
                acc2 = __builtin_amdgcn_mfma_f32_16x16x32_bf16(fL[ks+2], BH[ks+2], acc2, 0, 0, 0);
            }
            __builtin_amdgcn_s_setprio(0);
        }
        __syncthreads();   // bar2: vnew visible

        // ---- W (gamma-scaled vnew) B-fragments for M3 (all waves) ----
        bf16x8 WHf[2], WLf[2];
        #pragma unroll
        for (int ks2 = 0; ks2 < 2; ++ks2) {
            int off = lr * 128 + (((ks2 * 4 + lk) ^ (lr & 7)) << 4);
            WHf[ks2] = *(const bf16x8*)(WH + off);
            WLf[ks2] = *(const bf16x8*)(WL + off);
        }
        if (grp == 1) {
            // ---- M2b: o = dev*(k@S) + att@vnew ; store ----
            bf16x8 VHf[2], VLf[2];
            #pragma unroll
            for (int ks2 = 0; ks2 < 2; ++ks2) {
                int off = lr * 128 + (((ks2 * 4 + lk) ^ (lr & 7)) << 4);
                VHf[ks2] = *(const bf16x8*)(VH + off);
                VLf[ks2] = *(const bf16x8*)(VL + off);
            }
            f32x4 om;
            #pragma unroll
            for (int r = 0; r < 4; ++r) om[r] = (acc1[r] + acc2[r]) * dev4[r];
            #pragma unroll
            for (int ks2 = 0; ks2 < 2; ++ks2) {
                om = __builtin_amdgcn_mfma_f32_16x16x32_bf16(atA[ks2], VHf[ks2], om, 0, 0, 0);
                om = __builtin_amdgcn_mfma_f32_16x16x32_bf16(atA[ks2], VLf[ks2], om, 0, 0, 0);
            }
            size_t ob = ((size_t)bh * T_ + (size_t)cn * 64) * 128 + e0 + lr;
            #pragma unroll
            for (int r = 0; r < 4; ++r)
                obuf[ob + (size_t)(cw * 16 + lk * 4 + r) * 128] = f2bf(om[r]);
        }

        // ---- prefetch chunk cn+1 (role-split; hidden under M3) ----
        if (cn + 1 < N_) {
            size_t nb = ((size_t)bh * N_ + cn + 1) * 8192;
            size_t na = ((size_t)bh * N_ + cn + 1) * 4096;
            #pragma unroll
            for (int q = 0; q < 4; ++q) {
                int idx = tid + q * 512;
                u16x4 hh = *(const u16x4*)(khi + nb + (size_t)idx * 4);
                u16x4 ll = *(const u16x4*)(klo + nb + (size_t)idx * 4);
                #pragma unroll
                for (int j = 0; j < 4; ++j) { sh_[q][j] = hh[j]; sl_[q][j] = ll[j]; }
            }
            if (grp == 0) {
                #pragma unroll
                for (int ks = 0; ks < 4; ++ks) {
                    size_t off = nb + (size_t)(cw * 16 + lr) * 128 + ks * 32 + lk * 8;
                    fH[ks] = *(const bf16x8*)(kcdhi + off);
                    fL[ks] = *(const bf16x8*)(kcdlo + off);
                }
                #pragma unroll
                for (int r = 0; r < 4; ++r)
                    vnA[r] = vpr[nb + (size_t)(cw * 16 + lk * 4 + r) * 128 + e0 + lr];
            } else {
                #pragma unroll
                for (int ks = 0; ks < 4; ++ks) {
                    size_t off = nb + (size_t)(cw * 16 + lr) * 128 + ks * 32 + lk * 8;
                    fH[ks] = *(const bf16x8*)(khi + off);
                    fL[ks] = *(const bf16x8*)(klo + off);
                }
                #pragma unroll
                for (int ks2 = 0; ks2 < 2; ++ks2)
                    atA[ks2] = *(const bf16x8*)(att + na + (size_t)(cw * 16 + lr) * 64 + ks2 * 32 + lk * 8);
            }
        }

        // ---- M3: S = g64*S + k^T @ (gamma-scaled vnew); wave owns dk-tile w ----
        {
            #pragma unroll
            for (int r = 0; r < 4; ++r) Sacc[r] *= g64;
            int dk = w * 16 + lr;
            int du = dk >> 2, db = (dk & 3) << 2;
            bf16x8 tH[2], tL[2];
            #pragma unroll
            for (int ks2 = 0; ks2 < 2; ++ks2) {
                unsigned uv[8];
                #pragma unroll
                for (int j = 0; j < 8; ++j) {
                    int c = ks2 * 32 + lk * 8 + j;
                    uv[j] = *(const unsigned*)(KPc + c * 512 + (swzu(c, du) << 4) + db);
                }
                tH[ks2] = mk8((uv[0] & 0xffffu) | (uv[1] << 16), (uv[2] & 0xffffu) | (uv[3] << 16),
                              (uv[4] & 0xffffu) | (uv[5] << 16), (uv[6] & 0xffffu) | (uv[7] << 16));
                tL[ks2] = mk8((uv[0] >> 16) | (uv[1] & 0xffff0000u), (uv[2] >> 16) | (uv[3] & 0xffff0000u),
                              (uv[4] >> 16) | (uv[5] & 0xffff0000u), (uv[6] >> 16) | (uv[7] & 0xffff0000u));
            }
            f32x4 tmp = (f32x4){0.f, 0.f, 0.f, 0.f};
            __builtin_amdgcn_s_setprio(1);
            Sacc = __builtin_amdgcn_mfma_f32_16x16x32_bf16(tH[0], WHf[0], Sacc, 0, 0, 0);
            tmp  = __builtin_amdgcn_mfma_f32_16x16x32_bf16(tH[1], WHf[1], tmp,  0, 0, 0);
            Sacc = __builtin_amdgcn_mfma_f32_16x16x32_bf16(tH[0], WLf[0], Sacc, 0, 0, 0);
            tmp  = __builtin_amdgcn_mfma_f32_16x16x32_bf16(tH[1], WLf[1], tmp,  0, 0, 0);
            Sacc = __builtin_amdgcn_mfma_f32_16x16x32_bf16(tL[0], WHf[0], Sacc, 0, 0, 0);
            tmp  = __builtin_amdgcn_mfma_f32_16x16x32_bf16(tL[1], WHf[1], tmp,  0, 0, 0);
            __builtin_amdgcn_s_setprio(0);
            #pragma unroll
            for (int r = 0; r < 4; ++r) Sacc[r] += tmp[r];
        }

        // ---- stage chunk cn+1 -> other KP buffer ----
        if (cn + 1 < N_) {
            char* KPn = KP + ((cn + 1) & 1) * 32768;
            #pragma unroll
            for (int q = 0; q < 4; ++q) {
                int idx = tid + q * 512;
                int c = idx >> 5, un = idx & 31;
                uint4 pkd = {pk2((unsigned short)sh_[q][0], (unsigned short)sl_[q][0]),
                             pk2((unsigned short)sh_[q][1], (unsigned short)sl_[q][1]),
                             pk2((unsigned short)sh_[q][2], (unsigned short)sl_[q][2]),
                             pk2((unsigned short)sh_[q][3], (unsigned short)sl_[q][3])};
                *(uint4*)(KPn + c * 512 + (swzu(c, un) << 4)) = pkd;
            }
        }
        // next bar1 orders staging writes vs KP reads
    }
}

// =====================================================================
// Kernel 5: final — out = x + o @ W_read^T (o from bf16 obuf).
// =====================================================================
__launch_bounds__(256, 2)
__global__ void final_kernel(const float* __restrict__ X, const float* __restrict__ W,
                             const unsigned short* __restrict__ OB, float* __restrict__ out) {
    __shared__ float As[16][128];
    __shared__ float Bs[16][128];
    int bm = blockIdx.x, bn = blockIdx.y;
    int tid = threadIdx.x;
    int tx = tid & 15, ty = tid >> 4;
    float acc[8][8] = {};
    const float* Bg = W + (size_t)bn * 128 * D_;
    for (int kt = 0; kt < 64; ++kt) {
        int hh = kt >> 3;
        #pragma unroll
        for (int l = 0; l < 2; ++l) {
            int s = tid + l * 256;
            int row = s >> 2, c4 = (s & 3) << 2;
            int m = bm * 128 + row;
            int bb_ = m >> 13, t = m & 8191;
            int e0 = ((kt & 7) << 4) + c4;
            u16x4 av = *(const u16x4*)(OB + (((size_t)(bb_ * H_ + hh) * T_ + t) << 7) + e0);
            float4 bv = *(const float4*)(Bg + (size_t)row * D_ + kt * 16 + c4);
            As[c4 + 0][row] = bf2f(av[0]); As[c4 + 1][row] = bf2f(av[1]);
            As[c4 + 2][row] = bf2f(av[2]); As[c4 + 3][row] = bf2f(av[3]);
            Bs[c4 + 0][row] = bv.x; Bs[c4 + 1][row] = bv.y; Bs[c4 + 2][row] = bv.z; Bs[c4 + 3][row] = bv.w;
        }
        __syncthreads();
        #pragma unroll
        for (int kk = 0; kk < 16; ++kk) {
            float4 a0 = *(const float4*)&As[kk][ty * 8];
            float4 a1 = *(const float4*)&As[kk][ty * 8 + 4];
            float4 b0 = *(const float4*)&Bs[kk][tx * 8];
            float4 b1 = *(const float4*)&Bs[kk][tx * 8 + 4];
            float a[8] = {a0.x, a0.y, a0.z, a0.w, a1.x, a1.y, a1.z, a1.w};
            float bb[8] = {b0.x, b0.y, b0.z, b0.w, b1.x, b1.y, b1.z, b1.w};
            #pragma unroll
            for (int r = 0; r < 8; ++r)
                #pragma unroll
                for (int c = 0; c < 8; ++c)
                    acc[r][c] = fmaf(a[r], bb[c], acc[r][c]);
        }
        __syncthreads();
    }
    int m0 = bm * 128 + ty * 8;
    #pragma unroll
    for (int r = 0; r < 8; ++r) {
        int m = m0 + r;
        size_t xoff = (size_t)m * D_ + bn * 128 + tx * 8;
        float4 x0 = *(const float4*)(X + xoff);
        float4 x1 = *(const float4*)(X + xoff + 4);
        float4 o0 = {x0.x + acc[r][0], x0.y + acc[r][1], x0.z + acc[r][2], x0.w + acc[r][3]};
        float4 o1 = {x1.x + acc[r][4], x1.y + acc[r][5], x1.z + acc[r][6], x1.w + acc[r][7]};
        *(float4*)(out + xoff)     = o0;
        *(float4*)(out + xoff + 4) = o1;
    }
}

// =====================================================================
extern "C" void kernel_launch(void* const* d_in, const int* in_sizes, int n_in,
                              void* d_out, int out_size, void* d_ws, size_t ws_size,
                              hipStream_t stream) {
    const float* X   = (const float*)d_in[0];
    const float* Ww  = (const float*)d_in[1];
    const float* Wr  = (const float*)d_in[2];
    const float* Wb  = (const float*)d_in[3];
    const float* dec = (const float*)d_in[4];

    // workspace layout (bytes), total 252,182,528 (proven-fitting)
    char* ws = (char*)d_ws;
    unsigned short* khi  = (unsigned short*)(ws);                 // 32MB
    unsigned short* klo  = (unsigned short*)(ws + 33554432);      // 32MB
    float*          vb   = (float*)(ws + 67108864);               // 64MB  v -> v'
    unsigned short* kcdh = (unsigned short*)(ws + 134217728);     // 32MB
    unsigned short* kcdl = (unsigned short*)(ws + 167772160);     // 32MB
    unsigned short* attn = (unsigned short*)(ws + 201326592);     // 16MB
    float*          beta = (float*)(ws + 218103808);              // 0.5MB
    unsigned short* obuf = (unsigned short*)(ws + 218628096);     // 32MB
    if (ws_size < 252182528ull) return;

    hipFuncSetAttribute((const void*)chunk_kernel, hipFuncAttributeMaxDynamicSharedMemorySize, 65536);
    hipFuncSetAttribute((const void*)scan_kernel,  hipFuncAttributeMaxDynamicSharedMemorySize, 81920);

    hipLaunchKernelGGL(prep_kernel, dim3(B_ * T_), dim3(256), 0, stream, X, Wb, khi, klo, beta);
    hipLaunchKernelGGL(vproj_kernel, dim3(128, 8), dim3(256), 0, stream, X, Ww, beta, vb);
    hipLaunchKernelGGL(chunk_kernel, dim3(B_ * H_ * N_), dim3(256), 65536, stream,
                       khi, klo, vb, beta, dec, attn, kcdh, kcdl);
    hipLaunchKernelGGL(scan_kernel, dim3(128), dim3(512), 81920, stream,
                       khi, klo, vb, kcdh, kcdl, attn, dec, obuf);
    hipLaunchKernelGGL(final_kernel, dim3(128, 8), dim3(256), 0, stream, X, Wr, obuf, (float*)d_out);
}

// Round 7
// 1152.341 us; speedup vs baseline: 1.9529x; 1.3502x over previous
//
#include <hip/hip_runtime.h>
#include <stdint.h>

#define DEV static __device__ __forceinline__

typedef float          f32x4  __attribute__((ext_vector_type(4)));
typedef short          bf16x8 __attribute__((ext_vector_type(8)));
typedef unsigned short u16x4  __attribute__((ext_vector_type(4)));
typedef unsigned short u16x8  __attribute__((ext_vector_type(8)));

#define B_   2
#define T_   8192
#define D_   1024
#define H_   8
#define HD_  128
#define N_   128   /* chunks per (b,h) */

DEV float dot4(const float4& a, const float4& b) {
    return a.x * b.x + a.y * b.y + a.z * b.z + a.w * b.w;
}
DEV unsigned short f2bf(float f) {
    union { float f; unsigned u; } v; v.f = f;
    unsigned r = (v.u + 0x7fffu + ((v.u >> 16) & 1u)) >> 16;
    return (unsigned short)r;
}
DEV float bf2f(unsigned short u) {
    union { unsigned u; float f; } v; v.u = ((unsigned)u) << 16;
    return v.f;
}
DEV unsigned pk2(unsigned short h, unsigned short l) {
    return (unsigned)h | ((unsigned)l << 16);
}
DEV bf16x8 mk8(unsigned a, unsigned b, unsigned c, unsigned d) {
    union { unsigned u[4]; bf16x8 v; } t;
    t.u[0] = a; t.u[1] = b; t.u[2] = c; t.u[3] = d;
    return t.v;
}
DEV void cvt4(const float4 v, u16x4* h, u16x4* l) {
    const float* p = (const float*)&v;
    #pragma unroll
    for (int i = 0; i < 4; ++i) {
        unsigned short hv = f2bf(p[i]);
        (*h)[i] = hv;
        (*l)[i] = f2bf(p[i] - bf2f(hv));
    }
}
// k-tile LDS swizzle: 16B-unit index XORed with bits of row c (bijective per row)
DEV int swzu(int c, int u) { return u ^ (((c & 7) << 2) | ((c >> 3) & 3)); }

// Swizzled LDS rows of 512B (128 f32); swizzle per 16B unit: unit ^= (row&7).
DEV float4* r512(char* base, int r, int u) {
    return (float4*)(base + (r << 9) + ((u << 4) ^ ((r & 7) << 4)));
}

// =====================================================================
// Kernel 1: prep — L2-normalized k per head -> bf16 hi/lo; beta.
// =====================================================================
__launch_bounds__(256)
__global__ void prep_kernel(const float* __restrict__ X, const float* __restrict__ Wb,
                            unsigned short* __restrict__ khi, unsigned short* __restrict__ klo,
                            float* __restrict__ beta) {
    int bt = blockIdx.x;
    int b = bt >> 13, t = bt & 8191;
    __shared__ float xrow[D_];
    const float* xp = X + (size_t)bt * D_;
    for (int i = threadIdx.x; i < D_; i += 256) xrow[i] = xp[i];
    __syncthreads();
    int w = threadIdx.x >> 6, lane = threadIdx.x & 63;
    for (int h = w; h < H_; h += 4) {
        const float* xh = xrow + h * HD_;
        float a0 = xh[lane], a1 = xh[lane + 64];
        float s = a0 * a0 + a1 * a1;
        #pragma unroll
        for (int off = 32; off > 0; off >>= 1) s += __shfl_xor(s, off);
        float rn = 1.0f / fmaxf(sqrtf(s), 1e-12f);
        const float* wbh = Wb + (size_t)h * D_;
        float bs = 0.f;
        for (int i = lane; i < D_; i += 64) bs += xrow[i] * wbh[i];
        #pragma unroll
        for (int off = 32; off > 0; off >>= 1) bs += __shfl_xor(bs, off);
        float bet = 1.0f / (1.0f + expf(-bs));
        size_t kbase = ((size_t)(b * H_ + h) * T_ + t) * HD_;
        float x0 = a0 * rn, x1 = a1 * rn;
        unsigned short h0 = f2bf(x0), h1 = f2bf(x1);
        khi[kbase + lane]      = h0;
        khi[kbase + lane + 64] = h1;
        klo[kbase + lane]      = f2bf(x0 - bf2f(h0));
        klo[kbase + lane + 64] = f2bf(x1 - bf2f(h1));
        if (lane == 0) beta[(size_t)(b * H_ + h) * T_ + t] = bet;
    }
}

// =====================================================================
// Kernel 2: vproj v2 — v = beta*(x @ W_write^T) via split-bf16 MFMA.
// 128x128 tile, K=1024, KSTEP=64. On-the-fly f32->hi/lo LDS staging.
// grid (128 bm, 8 bn) x 256 thr (4 waves 2x2). dyn LDS 64KB.
// =====================================================================
__launch_bounds__(256, 2)
__global__ void vproj_kernel(const float* __restrict__ X, const float* __restrict__ W,
                             const float* __restrict__ beta, float* __restrict__ vb) {
    extern __shared__ char gs[];
    char* AH = gs;             // [128][64] bf16 hi, swizzled, 16KB
    char* AL = gs + 16384;
    char* BH = gs + 32768;
    char* BL = gs + 49152;     // 64KB
    int bm = blockIdx.x, bn = blockIdx.y;
    int tid = threadIdx.x;
    int w = tid >> 6, lr = tid & 15, lk = (tid & 63) >> 4;
    int wm = w >> 1, wn = w & 1;

    f32x4 acc[4][4];
    #pragma unroll
    for (int i = 0; i < 4; ++i)
        #pragma unroll
        for (int j = 0; j < 4; ++j) acc[i][j] = (f32x4){0.f, 0.f, 0.f, 0.f};

    for (int kt = 0; kt < 16; ++kt) {
        __syncthreads();   // protect LDS from previous iteration's readers
        #pragma unroll
        for (int q = 0; q < 8; ++q) {
            int f = tid + q * 256;            // 0..2047
            int row = f >> 4, kq = f & 15;    // 16 float4 per row
            float4 av = *(const float4*)(X + (size_t)(bm * 128 + row) * D_ + kt * 64 + kq * 4);
            float4 bv = *(const float4*)(W + (size_t)(bn * 128 + row) * D_ + kt * 64 + kq * 4);
            u16x4 ah, al, bh, bl;
            cvt4(av, &ah, &al);
            cvt4(bv, &bh, &bl);
            int off = row * 128 + ((((kq >> 1) ^ (row & 7))) << 4) + ((kq & 1) << 3);
            *(u16x4*)(AH + off) = ah; *(u16x4*)(AL + off) = al;
            *(u16x4*)(BH + off) = bh; *(u16x4*)(BL + off) = bl;
        }
        __syncthreads();
        #pragma unroll
        for (int ks = 0; ks < 2; ++ks) {
            bf16x8 aH[4], aL[4], bH[4], bL[4];
            #pragma unroll
            for (int mt = 0; mt < 4; ++mt) {
                int row = wm * 64 + mt * 16 + lr;
                int off = row * 128 + (((ks * 4 + lk) ^ (row & 7)) << 4);
                aH[mt] = *(const bf16x8*)(AH + off);
                aL[mt] = *(const bf16x8*)(AL + off);
            }
            #pragma unroll
            for (int nt = 0; nt < 4; ++nt) {
                int row = wn * 64 + nt * 16 + lr;
                int off = row * 128 + (((ks * 4 + lk) ^ (row & 7)) << 4);
                bH[nt] = *(const bf16x8*)(BH + off);
                bL[nt] = *(const bf16x8*)(BL + off);
            }
            #pragma unroll
            for (int mt = 0; mt < 4; ++mt)
                #pragma unroll
                for (int nt = 0; nt < 4; ++nt) {
                    acc[mt][nt] = __builtin_amdgcn_mfma_f32_16x16x32_bf16(aH[mt], bH[nt], acc[mt][nt], 0, 0, 0);
                    acc[mt][nt] = __builtin_amdgcn_mfma_f32_16x16x32_bf16(aH[mt], bL[nt], acc[mt][nt], 0, 0, 0);
                    acc[mt][nt] = __builtin_amdgcn_mfma_f32_16x16x32_bf16(aL[mt], bH[nt], acc[mt][nt], 0, 0, 0);
                }
        }
    }
    // epilogue: *beta, store to vb[bh][t][d]  (bn == head, n == d)
    #pragma unroll
    for (int mt = 0; mt < 4; ++mt)
        #pragma unroll
        for (int r = 0; r < 4; ++r) {
            int m = bm * 128 + wm * 64 + mt * 16 + lk * 4 + r;
            int b = m >> 13, t = m & 8191;
            float bet = beta[(size_t)(b * H_ + bn) * T_ + t];
            size_t ob = ((size_t)(b * H_ + bn) * T_ + t) * HD_;
            #pragma unroll
            for (int nt = 0; nt < 4; ++nt)
                vb[ob + wn * 64 + nt * 16 + lr] = acc[mt][nt][r] * bet;
        }
}

// =====================================================================
// Kernel 3: chunk — dots, attn(bf16), M, A=M^{-1},
//   kcd-negated (bf16 hi/lo), v' = A@v (f32 in place).
// =====================================================================
__launch_bounds__(256, 2)
__global__ void chunk_kernel(const unsigned short* __restrict__ khi,
                             const unsigned short* __restrict__ klo,
                             float* __restrict__ vb,
                             const float* __restrict__ beta_g,
                             const float* __restrict__ decay,
                             unsigned short* __restrict__ attn_g,
                             unsigned short* __restrict__ kcdhi_g,
                             unsigned short* __restrict__ kcdlo_g) {
    extern __shared__ char cs[];
    char*  sk = cs;                      // [64][128] f32 swz (32KB); later reused for v
    float* sa = (float*)(cs + 32768);    // [64][64] A
    float* sm = (float*)(cs + 49152);    // [64][64] M
    __shared__ float sb[64];
    __shared__ float swgt[64];

    int cid = blockIdx.x;
    int bh = cid >> 7, cn = cid & 127;
    int h = bh & 7;
    int tid = threadIdx.x;
    float dec = decay[h];
    float sg = 1.0f / (1.0f + expf(-dec));
    float lg = logf(sg);
    size_t base = (size_t)cid * 8192;

    #pragma unroll
    for (int lq = 0; lq < 4; ++lq) {
        int f = tid + lq * 256;
        int c = f >> 4, u0 = (f & 15) << 1;
        u16x8 hh = *(const u16x8*)(khi + base + (size_t)f * 8);
        u16x8 ll = *(const u16x8*)(klo + base + (size_t)f * 8);
        float4 v0 = {bf2f(hh[0]) + bf2f(ll[0]), bf2f(hh[1]) + bf2f(ll[1]),
                     bf2f(hh[2]) + bf2f(ll[2]), bf2f(hh[3]) + bf2f(ll[3])};
        float4 v1 = {bf2f(hh[4]) + bf2f(ll[4]), bf2f(hh[5]) + bf2f(ll[5]),
                     bf2f(hh[6]) + bf2f(ll[6]), bf2f(hh[7]) + bf2f(ll[7])};
        *r512(sk, c, u0)     = v0;
        *r512(sk, c, u0 + 1) = v1;
    }
    if (tid < 64) {
        float bv = beta_g[(size_t)bh * T_ + cn * 64 + tid];
        sb[tid] = bv;
        swgt[tid] = bv * expf((float)(tid + 1) * lg);
    }
    __syncthreads();

    int bi = tid >> 4, bj = tid & 15;
    float dacc[4][4] = {};
    for (int u = 0; u < 32; ++u) {
        float4 ka[4], kc[4];
        #pragma unroll
        for (int i = 0; i < 4; ++i) ka[i] = *r512(sk, bi * 4 + i, u);
        #pragma unroll
        for (int j = 0; j < 4; ++j) kc[j] = *r512(sk, bj + 16 * j, u);
        #pragma unroll
        for (int i = 0; i < 4; ++i)
            #pragma unroll
            for (int j = 0; j < 4; ++j)
                dacc[i][j] += dot4(ka[i], kc[j]);
    }
    size_t abase = (size_t)cid * 4096;
    #pragma unroll
    for (int i = 0; i < 4; ++i) {
        int gi = bi * 4 + i;
        #pragma unroll
        for (int j = 0; j < 4; ++j) {
            int gj = bj + 16 * j;
            float dv = dacc[i][j];
            float dfac = expf((float)(gi - gj) * lg);
            attn_g[abase + (size_t)gi * 64 + gj] = (gi >= gj) ? f2bf(dv * dfac) : (unsigned short)0;
            sm[gi * 64 + gj] = (gj < gi) ? sb[gi] * dv * dfac : ((gi == gj) ? 1.f : 0.f);
        }
    }
    __syncthreads();

    if (tid < 64) {
        int j = tid;
        for (int i = 0; i < j; ++i) sa[i * 64 + j] = 0.f;
        sa[j * 64 + j] = 1.f;
        for (int i = j + 1; i < 64; ++i) {
            float s = 0.f;
            for (int p = j; p < i; ++p) s += sm[i * 64 + p] * sa[p * 64 + j];
            sa[i * 64 + j] = -s;
        }
    }
    __syncthreads();

    int ti = tid >> 4, te = tid & 15;
    {
        float ko[4][8] = {};
        for (int p = 0; p < 64; ++p) {
            float w = swgt[p];
            float4 k0 = *r512(sk, p, te * 2);
            float4 k1 = *r512(sk, p, te * 2 + 1);
            float kv[8] = {k0.x, k0.y, k0.z, k0.w, k1.x, k1.y, k1.z, k1.w};
            float a0 = sa[(ti * 4 + 0) * 64 + p] * w;
            float a1 = sa[(ti * 4 + 1) * 64 + p] * w;
            float a2 = sa[(ti * 4 + 2) * 64 + p] * w;
            float a3 = sa[(ti * 4 + 3) * 64 + p] * w;
            #pragma unroll
            for (int e = 0; e < 8; ++e) {
                ko[0][e] = fmaf(a0, kv[e], ko[0][e]);
                ko[1][e] = fmaf(a1, kv[e], ko[1][e]);
                ko[2][e] = fmaf(a2, kv[e], ko[2][e]);
                ko[3][e] = fmaf(a3, kv[e], ko[3][e]);
            }
        }
        #pragma unroll
        for (int i = 0; i < 4; ++i) {
            u16x8 hh, ll;
            #pragma unroll
            for (int e = 0; e < 8; ++e) {
                float t = -ko[i][e];
                unsigned short hv = f2bf(t);
                hh[e] = hv;
                ll[e] = f2bf(t - bf2f(hv));
            }
            size_t off = base + (size_t)(ti * 4 + i) * 128 + te * 8;
            *(u16x8*)(kcdhi_g + off) = hh;
            *(u16x8*)(kcdlo_g + off) = ll;
        }
    }
    __syncthreads();

    #pragma unroll
    for (int lq = 0; lq < 8; ++lq) {
        int f = tid + lq * 256;
        int r = f >> 5, u = f & 31;
        *r512(sk, r, u) = ((const float4*)(vb + base))[f];
    }
    __syncthreads();

    {
        float vo[4][8] = {};
        for (int p = 0; p < 64; ++p) {
            float4 v0 = *r512(sk, p, te * 2);
            float4 v1 = *r512(sk, p, te * 2 + 1);
            float vv[8] = {v0.x, v0.y, v0.z, v0.w, v1.x, v1.y, v1.z, v1.w};
            float a0 = sa[(ti * 4 + 0) * 64 + p];
            float a1 = sa[(ti * 4 + 1) * 64 + p];
            float a2 = sa[(ti * 4 + 2) * 64 + p];
            float a3 = sa[(ti * 4 + 3) * 64 + p];
            #pragma unroll
            for (int e = 0; e < 8; ++e) {
                vo[0][e] = fmaf(a0, vv[e], vo[0][e]);
                vo[1][e] = fmaf(a1, vv[e], vo[1][e]);
                vo[2][e] = fmaf(a2, vv[e], vo[2][e]);
                vo[3][e] = fmaf(a3, vv[e], vo[3][e]);
            }
        }
        #pragma unroll
        for (int i = 0; i < 4; ++i) {
            float4 lo = {vo[i][0], vo[i][1], vo[i][2], vo[i][3]};
            float4 hi = {vo[i][4], vo[i][5], vo[i][6], vo[i][7]};
            size_t off = base + (size_t)(ti * 4 + i) * 128 + te * 8;
            *(float4*)(vb + off)     = lo;
            *(float4*)(vb + off + 4) = hi;
        }
    }
}

// =====================================================================
// Kernel 4: scan v3 — 8-wave role-split (unchanged from r6).
// =====================================================================
__launch_bounds__(512, 1)
__global__ void scan_kernel(const unsigned short* __restrict__ khi,
                            const unsigned short* __restrict__ klo,
                            const float* __restrict__ vpr,
                            const unsigned short* __restrict__ kcdhi,
                            const unsigned short* __restrict__ kcdlo,
                            const unsigned short* __restrict__ att,
                            const float* __restrict__ decay,
                            unsigned short* __restrict__ obuf) {
    extern __shared__ char ls[];
    char* KP = ls;               // 2 x [c:64][dk-u32:128] packed hi|lo<<16, swz; 2x32KB
    char* SH = ls + 65536;       // S^T hi [e:16][dk:128] bf16, 4KB
    char* SL = ls + 69632;
    char* VH = ls + 73728;       // vnew^T hi [e:16][c:64] bf16, 2KB
    char* VL = ls + 75776;
    char* WH = ls + 77824;       // vnew^T * gamma^{63-c} hi
    char* WL = ls + 79872;       // total 81920

    int bid = blockIdx.x;                 // 0..127
    int h7 = bid & 7;
    int strip = (bid >> 3) & 7;
    int bh = ((bid >> 6) << 3) + h7;
    int e0 = strip * 16;
    int tid = threadIdx.x;
    int w = tid >> 6, l = tid & 63, lr = l & 15, lk = l >> 4;
    int grp = w >> 2, cw = w & 3;
    float dec = decay[bh & 7];
    float sg = 1.0f / (1.0f + expf(-dec));
    float lg = logf(sg);
    float g64 = expf(64.f * lg);
    float dev4[4], gw4[4];
    #pragma unroll
    for (int r = 0; r < 4; ++r) {
        int c = cw * 16 + lk * 4 + r;
        dev4[r] = expf((float)(c + 1) * lg);
        gw4[r]  = expf((float)(63 - c) * lg);
    }

    f32x4 Sacc = (f32x4){0.f, 0.f, 0.f, 0.f};

    unsigned sh_[4][4], sl_[4][4];
    bf16x8 fH[4], fL[4];
    bf16x8 atA[2];
    f32x4 vnA;

    {
        size_t nb = (size_t)bh * N_ * 8192;
        size_t na = (size_t)bh * N_ * 4096;
        #pragma unroll
        for (int q = 0; q < 4; ++q) {
            int idx = tid + q * 512;
            u16x4 hh = *(const u16x4*)(khi + nb + (size_t)idx * 4);
            u16x4 ll = *(const u16x4*)(klo + nb + (size_t)idx * 4);
            #pragma unroll
            for (int j = 0; j < 4; ++j) { sh_[q][j] = hh[j]; sl_[q][j] = ll[j]; }
        }
        if (grp == 0) {
            #pragma unroll
            for (int ks = 0; ks < 4; ++ks) {
                size_t off = nb + (size_t)(cw * 16 + lr) * 128 + ks * 32 + lk * 8;
                fH[ks] = *(const bf16x8*)(kcdhi + off);
                fL[ks] = *(const bf16x8*)(kcdlo + off);
            }
            #pragma unroll
            for (int r = 0; r < 4; ++r)
                vnA[r] = vpr[nb + (size_t)(cw * 16 + lk * 4 + r) * 128 + e0 + lr];
        } else {
            #pragma unroll
            for (int ks = 0; ks < 4; ++ks) {
                size_t off = nb + (size_t)(cw * 16 + lr) * 128 + ks * 32 + lk * 8;
                fH[ks] = *(const bf16x8*)(khi + off);
                fL[ks] = *(const bf16x8*)(klo + off);
            }
            #pragma unroll
            for (int ks2 = 0; ks2 < 2; ++ks2)
                atA[ks2] = *(const bf16x8*)(att + na + (size_t)(cw * 16 + lr) * 64 + ks2 * 32 + lk * 8);
        }
        #pragma unroll
        for (int q = 0; q < 4; ++q) {
            int idx = tid + q * 512;
            int c = idx >> 5, un = idx & 31;
            uint4 pkd = {pk2((unsigned short)sh_[q][0], (unsigned short)sl_[q][0]),
                         pk2((unsigned short)sh_[q][1], (unsigned short)sl_[q][1]),
                         pk2((unsigned short)sh_[q][2], (unsigned short)sl_[q][2]),
                         pk2((unsigned short)sh_[q][3], (unsigned short)sl_[q][3])};
            *(uint4*)(KP + c * 512 + (swzu(c, un) << 4)) = pkd;
        }
    }

    for (int cn = 0; cn < N_; ++cn) {
        const char* KPc = KP + (cn & 1) * 32768;

        {
            u16x4 h4, l4;
            #pragma unroll
            for (int r = 0; r < 4; ++r) {
                unsigned short hv = f2bf(Sacc[r]);
                h4[r] = hv;
                l4[r] = f2bf(Sacc[r] - bf2f(hv));
            }
            int unit = 2 * w + (lk >> 1);
            int off = lr * 256 + ((unit ^ (lr & 7)) << 4) + ((lk & 1) << 3);
            *(u16x4*)(SH + off) = h4;
            *(u16x4*)(SL + off) = l4;
        }
        __syncthreads();   // bar1

        bf16x8 BH[4], BL[4];
        #pragma unroll
        for (int ks = 0; ks < 4; ++ks) {
            int off = lr * 256 + (((ks * 4 + lk) ^ (lr & 7)) << 4);
            BH[ks] = *(const bf16x8*)(SH + off);
            BL[ks] = *(const bf16x8*)(SL + off);
        }
        f32x4 acc1, acc2;
        if (grp == 0) {
            acc1 = vnA; acc2 = (f32x4){0.f, 0.f, 0.f, 0.f};
            __builtin_amdgcn_s_setprio(1);
            #pragma unroll
            for (int ks = 0; ks < 2; ++ks) {
                acc1 = __builtin_amdgcn_mfma_f32_16x16x32_bf16(fH[ks], BH[ks], acc1, 0, 0, 0);
                acc2 = __builtin_amdgcn_mfma_f32_16x16x32_bf16(fH[ks+2], BH[ks+2], acc2, 0, 0, 0);
                acc1 = __builtin_amdgcn_mfma_f32_16x16x32_bf16(fH[ks], BL[ks], acc1, 0, 0, 0);
                acc2 = __builtin_amdgcn_mfma_f32_16x16x32_bf16(fH[ks+2], BL[ks+2], acc2, 0, 0, 0);
                acc1 = __builtin_amdgcn_mfma_f32_16x16x32_bf16(fL[ks], BH[ks], acc1, 0, 0, 0);
                acc2 = __builtin_amdgcn_mfma_f32_16x16x32_bf16(fL[ks+2], BH[ks+2], acc2, 0, 0, 0);
            }
            __builtin_amdgcn_s_setprio(0);
            u16x4 h4, l4, wh4, wl4;
            #pragma unroll
            for (int r = 0; r < 4; ++r) {
                float vv = acc1[r] + acc2[r];
                unsigned short hv = f2bf(vv);
                h4[r] = hv; l4[r] = f2bf(vv - bf2f(hv));
                float wv = vv * gw4[r];
                unsigned short wh = f2bf(wv);
                wh4[r] = wh; wl4[r] = f2bf(wv - bf2f(wh));
            }
            int cu = 2 * cw + (lk >> 1);
            int off = lr * 128 + ((cu ^ (lr & 7)) << 4) + ((lk & 1) << 3);
            *(u16x4*)(VH + off) = h4;  *(u16x4*)(VL + off) = l4;
            *(u16x4*)(WH + off) = wh4; *(u16x4*)(WL + off) = wl4;
        } else {
            acc1 = (f32x4){0.f, 0.f, 0.f, 0.f}; acc2 = acc1;
            __builtin_amdgcn_s_setprio(1);
            #pragma unroll
            for (int ks = 0; ks < 2; ++ks) {
                acc1 = __builtin_amdgcn_mfma_f32_16x16x32_bf16(fH[ks], BH[ks], acc1, 0, 0, 0);
                acc2 = __builtin_amdgcn_mfma_f32_16x16x32_bf16(fH[ks+2], BH[ks+2], acc2, 0, 0, 0);
                acc1 = __builtin_amdgcn_mfma_f32_16x16x32_bf16(fH[ks], BL[ks], acc1, 0, 0, 0);
                acc2 = __builtin_amdgcn_mfma_f32_16x16x32_bf16(fH[ks+2], BL[ks+2], acc2, 0, 0, 0);
                acc1 = __builtin_amdgcn_mfma_f32_16x16x32_bf16(fL[ks], BH[ks], acc1, 0, 0, 0);
                acc2 = __builtin_amdgcn_mfma_f32_16x16x32_bf16(fL[ks+2], BH[ks+2], acc2, 0, 0, 0);
            }
            __builtin_amdgcn_s_setprio(0);
        }
        __syncthreads();   // bar2

        bf16x8 WHf[2], WLf[2];
        #pragma unroll
        for (int ks2 = 0; ks2 < 2; ++ks2) {
            int off = lr * 128 + (((ks2 * 4 + lk) ^ (lr & 7)) << 4);
            WHf[ks2] = *(const bf16x8*)(WH + off);
            WLf[ks2] = *(const bf16x8*)(WL + off);
        }
        if (grp == 1) {
            bf16x8 VHf[2], VLf[2];
            #pragma unroll
            for (int ks2 = 0; ks2 < 2; ++ks2) {
                int off = lr * 128 + (((ks2 * 4 + lk) ^ (lr & 7)) << 4);
                VHf[ks2] = *(const bf16x8*)(VH + off);
                VLf[ks2] = *(const bf16x8*)(VL + off);
            }
            f32x4 om;
            #pragma unroll
            for (int r = 0; r < 4; ++r) om[r] = (acc1[r] + acc2[r]) * dev4[r];
            #pragma unroll
            for (int ks2 = 0; ks2 < 2; ++ks2) {
                om = __builtin_amdgcn_mfma_f32_16x16x32_bf16(atA[ks2], VHf[ks2], om, 0, 0, 0);
                om = __builtin_amdgcn_mfma_f32_16x16x32_bf16(atA[ks2], VLf[ks2], om, 0, 0, 0);
            }
            size_t ob = ((size_t)bh * T_ + (size_t)cn * 64) * 128 + e0 + lr;
            #pragma unroll
            for (int r = 0; r < 4; ++r)
                obuf[ob + (size_t)(cw * 16 + lk * 4 + r) * 128] = f2bf(om[r]);
        }

        if (cn + 1 < N_) {
            size_t nb = ((size_t)bh * N_ + cn + 1) * 8192;
            size_t na = ((size_t)bh * N_ + cn + 1) * 4096;
            #pragma unroll
            for (int q = 0; q < 4; ++q) {
                int idx = tid + q * 512;
                u16x4 hh = *(const u16x4*)(khi + nb + (size_t)idx * 4);
                u16x4 ll = *(const u16x4*)(klo + nb + (size_t)idx * 4);
                #pragma unroll
                for (int j = 0; j < 4; ++j) { sh_[q][j] = hh[j]; sl_[q][j] = ll[j]; }
            }
            if (grp == 0) {
                #pragma unroll
                for (int ks = 0; ks < 4; ++ks) {
                    size_t off = nb + (size_t)(cw * 16 + lr) * 128 + ks * 32 + lk * 8;
                    fH[ks] = *(const bf16x8*)(kcdhi + off);
                    fL[ks] = *(const bf16x8*)(kcdlo + off);
                }
                #pragma unroll
                for (int r = 0; r < 4; ++r)
                    vnA[r] = vpr[nb + (size_t)(cw * 16 + lk * 4 + r) * 128 + e0 + lr];
            } else {
                #pragma unroll
                for (int ks = 0; ks < 4; ++ks) {
                    size_t off = nb + (size_t)(cw * 16 + lr) * 128 + ks * 32 + lk * 8;
                    fH[ks] = *(const bf16x8*)(khi + off);
                    fL[ks] = *(const bf16x8*)(klo + off);
                }
                #pragma unroll
                for (int ks2 = 0; ks2 < 2; ++ks2)
                    atA[ks2] = *(const bf16x8*)(att + na + (size_t)(cw * 16 + lr) * 64 + ks2 * 32 + lk * 8);
            }
        }

        {
            #pragma unroll
            for (int r = 0; r < 4; ++r) Sacc[r] *= g64;
            int dk = w * 16 + lr;
            int du = dk >> 2, db = (dk & 3) << 2;
            bf16x8 tH[2], tL[2];
            #pragma unroll
            for (int ks2 = 0; ks2 < 2; ++ks2) {
                unsigned uv[8];
                #pragma unroll
                for (int j = 0; j < 8; ++j) {
                    int c = ks2 * 32 + lk * 8 + j;
                    uv[j] = *(const unsigned*)(KPc + c * 512 + (swzu(c, du) << 4) + db);
                }
                tH[ks2] = mk8((uv[0] & 0xffffu) | (uv[1] << 16), (uv[2] & 0xffffu) | (uv[3] << 16),
                              (uv[4] & 0xffffu) | (uv[5] << 16), (uv[6] & 0xffffu) | (uv[7] << 16));
                tL[ks2] = mk8((uv[0] >> 16) | (uv[1] & 0xffff0000u), (uv[2] >> 16) | (uv[3] & 0xffff0000u),
                              (uv[4] >> 16) | (uv[5] & 0xffff0000u), (uv[6] >> 16) | (uv[7] & 0xffff0000u));
            }
            f32x4 tmp = (f32x4){0.f, 0.f, 0.f, 0.f};
            __builtin_amdgcn_s_setprio(1);
            Sacc = __builtin_amdgcn_mfma_f32_16x16x32_bf16(tH[0], WHf[0], Sacc, 0, 0, 0);
            tmp  = __builtin_amdgcn_mfma_f32_16x16x32_bf16(tH[1], WHf[1], tmp,  0, 0, 0);
            Sacc = __builtin_amdgcn_mfma_f32_16x16x32_bf16(tH[0], WLf[0], Sacc, 0, 0, 0);
            tmp  = __builtin_amdgcn_mfma_f32_16x16x32_bf16(tH[1], WLf[1], tmp,  0, 0, 0);
            Sacc = __builtin_amdgcn_mfma_f32_16x16x32_bf16(tL[0], WHf[0], Sacc, 0, 0, 0);
            tmp  = __builtin_amdgcn_mfma_f32_16x16x32_bf16(tL[1], WHf[1], tmp,  0, 0, 0);
            __builtin_amdgcn_s_setprio(0);
            #pragma unroll
            for (int r = 0; r < 4; ++r) Sacc[r] += tmp[r];
        }

        if (cn + 1 < N_) {
            char* KPn = KP + ((cn + 1) & 1) * 32768;
            #pragma unroll
            for (int q = 0; q < 4; ++q) {
                int idx = tid + q * 512;
                int c = idx >> 5, un = idx & 31;
                uint4 pkd = {pk2((unsigned short)sh_[q][0], (unsigned short)sl_[q][0]),
                             pk2((unsigned short)sh_[q][1], (unsigned short)sl_[q][1]),
                             pk2((unsigned short)sh_[q][2], (unsigned short)sl_[q][2]),
                             pk2((unsigned short)sh_[q][3], (unsigned short)sl_[q][3])};
                *(uint4*)(KPn + c * 512 + (swzu(c, un) << 4)) = pkd;
            }
        }
    }
}

// =====================================================================
// Kernel 5: final v2 — out = x + o @ W_read^T via MFMA.
// A = obuf bf16 (single plane), B = Wr f32 -> hi/lo staged. 2 products.
// grid (128, 8) x 256 thr. dyn LDS 48KB.
// =====================================================================
__launch_bounds__(256, 2)
__global__ void final_kernel(const float* __restrict__ X, const float* __restrict__ W,
                             const unsigned short* __restrict__ OB, float* __restrict__ out) {
    extern __shared__ char gs[];
    char* AO = gs;             // [128][64] bf16, swizzled, 16KB
    char* BH = gs + 16384;
    char* BL = gs + 32768;     // 48KB
    int bm = blockIdx.x, bn = blockIdx.y;
    int tid = threadIdx.x;
    int w = tid >> 6, lr = tid & 15, lk = (tid & 63) >> 4;
    int wm = w >> 1, wn = w & 1;

    f32x4 acc[4][4];
    #pragma unroll
    for (int i = 0; i < 4; ++i)
        #pragma unroll
        for (int j = 0; j < 4; ++j) acc[i][j] = (f32x4){0.f, 0.f, 0.f, 0.f};

    for (int kt = 0; kt < 16; ++kt) {
        int hh = kt >> 1, e0g = (kt & 1) * 64;
        __syncthreads();
        #pragma unroll
        for (int q = 0; q < 4; ++q) {
            int f = tid + q * 256;            // 0..1023
            int row = f >> 3, un = f & 7;     // 8 u16x8 per row
            int m = bm * 128 + row;
            int b = m >> 13, t = m & 8191;
            u16x8 av = *(const u16x8*)(OB + (((size_t)(b * H_ + hh) * T_ + t) << 7) + e0g + un * 8);
            int off = row * 128 + ((un ^ (row & 7)) << 4);
            *(u16x8*)(AO + off) = av;
        }
        #pragma unroll
        for (int q = 0; q < 8; ++q) {
            int f = tid + q * 256;
            int row = f >> 4, kq = f & 15;
            float4 bv = *(const float4*)(W + (size_t)(bn * 128 + row) * D_ + kt * 64 + kq * 4);
            u16x4 bh, bl;
            cvt4(bv, &bh, &bl);
            int off = row * 128 + ((((kq >> 1) ^ (row & 7))) << 4) + ((kq & 1) << 3);
            *(u16x4*)(BH + off) = bh; *(u16x4*)(BL + off) = bl;
        }
        __syncthreads();
        #pragma unroll
        for (int ks = 0; ks < 2; ++ks) {
            bf16x8 aO[4], bH[4], bL[4];
            #pragma unroll
            for (int mt = 0; mt < 4; ++mt) {
                int row = wm * 64 + mt * 16 + lr;
                int off = row * 128 + (((ks * 4 + lk) ^ (row & 7)) << 4);
                aO[mt] = *(const bf16x8*)(AO + off);
            }
            #pragma unroll
            for (int nt = 0; nt < 4; ++nt) {
                int row = wn * 64 + nt * 16 + lr;
                int off = row * 128 + (((ks * 4 + lk) ^ (row & 7)) << 4);
                bH[nt] = *(const bf16x8*)(BH + off);
                bL[nt] = *(const bf16x8*)(BL + off);
            }
            #pragma unroll
            for (int mt = 0; mt < 4; ++mt)
                #pragma unroll
                for (int nt = 0; nt < 4; ++nt) {
                    acc[mt][nt] = __builtin_amdgcn_mfma_f32_16x16x32_bf16(aO[mt], bH[nt], acc[mt][nt], 0, 0, 0);
                    acc[mt][nt] = __builtin_amdgcn_mfma_f32_16x16x32_bf16(aO[mt], bL[nt], acc[mt][nt], 0, 0, 0);
                }
        }
    }
    // epilogue: out = X + acc
    #pragma unroll
    for (int mt = 0; mt < 4; ++mt)
        #pragma unroll
        for (int r = 0; r < 4; ++r) {
            int m = bm * 128 + wm * 64 + mt * 16 + lk * 4 + r;
            size_t xo = (size_t)m * D_ + bn * 128;
            #pragma unroll
            for (int nt = 0; nt < 4; ++nt) {
                int n = wn * 64 + nt * 16 + lr;
                out[xo + n] = X[xo + n] + acc[mt][nt][r];
            }
        }
}

// =====================================================================
extern "C" void kernel_launch(void* const* d_in, const int* in_sizes, int n_in,
                              void* d_out, int out_size, void* d_ws, size_t ws_size,
                              hipStream_t stream) {
    const float* X   = (const float*)d_in[0];
    const float* Ww  = (const float*)d_in[1];
    const float* Wr  = (const float*)d_in[2];
    const float* Wb  = (const float*)d_in[3];
    const float* dec = (const float*)d_in[4];

    // workspace layout (bytes), total 252,182,528 (proven-fitting)
    char* ws = (char*)d_ws;
    unsigned short* khi  = (unsigned short*)(ws);                 // 32MB
    unsigned short* klo  = (unsigned short*)(ws + 33554432);      // 32MB
    float*          vb   = (float*)(ws + 67108864);               // 64MB  v -> v'
    unsigned short* kcdh = (unsigned short*)(ws + 134217728);     // 32MB
    unsigned short* kcdl = (unsigned short*)(ws + 167772160);     // 32MB
    unsigned short* attn = (unsigned short*)(ws + 201326592);     // 16MB
    float*          beta = (float*)(ws + 218103808);              // 0.5MB
    unsigned short* obuf = (unsigned short*)(ws + 218628096);     // 32MB
    if (ws_size < 252182528ull) return;

    hipFuncSetAttribute((const void*)vproj_kernel, hipFuncAttributeMaxDynamicSharedMemorySize, 65536);
    hipFuncSetAttribute((const void*)chunk_kernel, hipFuncAttributeMaxDynamicSharedMemorySize, 65536);
    hipFuncSetAttribute((const void*)scan_kernel,  hipFuncAttributeMaxDynamicSharedMemorySize, 81920);
    hipFuncSetAttribute((const void*)final_kernel, hipFuncAttributeMaxDynamicSharedMemorySize, 49152);

    hipLaunchKernelGGL(prep_kernel, dim3(B_ * T_), dim3(256), 0, stream, X, Wb, khi, klo, beta);
    hipLaunchKernelGGL(vproj_kernel, dim3(128, 8), dim3(256), 65536, stream, X, Ww, beta, vb);
    hipLaunchKernelGGL(chunk_kernel, dim3(B_ * H_ * N_), dim3(256), 65536, stream,
                       khi, klo, vb, beta, dec, attn, kcdh, kcdl);
    hipLaunchKernelGGL(scan_kernel, dim3(128), dim3(512), 81920, stream,
                       khi, klo, vb, kcdh, kcdl, attn, dec, obuf);
    hipLaunchKernelGGL(final_kernel, dim3(128, 8), dim3(256), 49152, stream, X, Wr, obuf, (float*)d_out);
}